// Round 1
// baseline (24196.384 us; speedup 1.0000x reference)
//
#include <hip/hip_runtime.h>
#include <math.h>

#define D 768
#define NH 12
#define DH 64
#define DEPTH 12
#define TMAX 197
#define NPATCH 196
#define BATCH 32
#define DFF 3072
#define NC 1000
#define QSTRIDE 2304   // 3*D
#define SCALE 0.125f
#define EPSF 1e-6f

// ---------------- utility ----------------

__device__ __forceinline__ float block_reduce_sum(float v, float* red, int tid) {
  red[tid] = v; __syncthreads();
  #pragma unroll
  for (int o = 128; o > 0; o >>= 1) { if (tid < o) red[tid] += red[tid + o]; __syncthreads(); }
  float r = red[0]; __syncthreads();
  return r;
}

__global__ void fail_kernel(float* out) { out[0] = 1.0e6f; }

__global__ void init_kernel(int* si, float* sf) {
  si[0] = TMAX;  // tok (N+1)
  si[1] = 0;     // prev_mass valid
  si[2] = 0;     // prune flag this layer
  sf[0] = 0.f;   // prev_mass
}

// ---------------- embed ----------------

__global__ void im2col_kernel(const float* __restrict__ x, float* __restrict__ Aim) {
  int p = blockIdx.x, b = blockIdx.y;
  int py = p / 14, px = p % 14;
  float* dst = Aim + ((size_t)b * NPATCH + p) * D;
  for (int k = threadIdx.x; k < D; k += 256) {
    int c = k >> 8; int rem = k & 255; int i = rem >> 4; int j = rem & 15;
    dst[k] = x[(((size_t)b * 3 + c) * 224 + py * 16 + i) * 224 + px * 16 + j];
  }
}

__global__ void wtrans_kernel(const float* __restrict__ pw, float* __restrict__ BT) {
  size_t idx = (size_t)blockIdx.x * 256 + threadIdx.x;
  if (idx >= (size_t)D * D) return;
  int k = (int)(idx / D), d = (int)(idx % D);
  BT[idx] = pw[(size_t)d * D + k];
}

__global__ void assemble_kernel(const float* __restrict__ PE, const float* __restrict__ cls,
                                const float* __restrict__ pos, float* __restrict__ X) {
  int t = blockIdx.x, b = blockIdx.y; int tid = threadIdx.x;
  float* xp = X + ((size_t)(b * TMAX) + t) * D;
  for (int k = tid; k < D; k += 256) {
    float v = (t == 0) ? cls[k] : PE[((size_t)(b * NPATCH) + (t - 1)) * D + k];
    xp[k] = v + pos[(size_t)t * D + k];
  }
}

// ---------------- layernorm ----------------

__global__ void ln_kernel(const float* __restrict__ Xin, float* __restrict__ Xout,
                          const float* __restrict__ wgt, const float* __restrict__ bsh,
                          const int* __restrict__ si) {
  int row = blockIdx.x;
  if ((row % TMAX) >= si[0]) return;
  __shared__ float red[256];
  int tid = threadIdx.x;
  const float* xp = Xin + (size_t)row * D;
  float v0 = xp[tid], v1 = xp[tid + 256], v2 = xp[tid + 512];
  float mu = block_reduce_sum(v0 + v1 + v2, red, tid) * (1.0f / 768.0f);
  float d0 = v0 - mu, d1 = v1 - mu, d2 = v2 - mu;
  float var = block_reduce_sum(d0 * d0 + d1 * d1 + d2 * d2, red, tid) * (1.0f / 768.0f);
  float inv = 1.0f / sqrtf(var + EPSF);
  float* op = Xout + (size_t)row * D;
  op[tid]       = d0 * inv * wgt[tid]       + bsh[tid];
  op[tid + 256] = d1 * inv * wgt[tid + 256] + bsh[tid + 256];
  op[tid + 512] = d2 * inv * wgt[tid + 512] + bsh[tid + 512];
}

__global__ void lnfinal_kernel(const float* __restrict__ X, float* __restrict__ CLSb,
                               const float* __restrict__ wgt, const float* __restrict__ bsh) {
  int b = blockIdx.x; int tid = threadIdx.x;
  __shared__ float red[256];
  const float* xp = X + (size_t)b * TMAX * D;  // row t=0
  float v0 = xp[tid], v1 = xp[tid + 256], v2 = xp[tid + 512];
  float mu = block_reduce_sum(v0 + v1 + v2, red, tid) * (1.0f / 768.0f);
  float d0 = v0 - mu, d1 = v1 - mu, d2 = v2 - mu;
  float var = block_reduce_sum(d0 * d0 + d1 * d1 + d2 * d2, red, tid) * (1.0f / 768.0f);
  float inv = 1.0f / sqrtf(var + EPSF);
  float* op = CLSb + (size_t)b * D;
  op[tid]       = d0 * inv * wgt[tid]       + bsh[tid];
  op[tid + 256] = d1 * inv * wgt[tid + 256] + bsh[tid + 256];
  op[tid + 512] = d2 * inv * wgt[tid + 512] + bsh[tid + 512];
}

// ---------------- f32 GEMM: C[M,N] = act(A[M,K] @ Bw[K,N] + bias [+ Rsrc]) ----------------
// 128x64 tile, 256 threads, 8x4 acc per thread.

#define BM 128
#define BN 64
#define BK 16

template<int ACT, int RES>
__global__ __launch_bounds__(256, 2)
void gemm_kernel(const float* __restrict__ A, const float* __restrict__ Bw,
                 const float* __restrict__ bias, const float* __restrict__ Rsrc,
                 float* __restrict__ C, int M, int K, int N) {
  __shared__ float As[BK][BM + 4];   // [k][m], row stride 132 (16B aligned)
  __shared__ float Bs[BK][BN];
  int tid = threadIdx.x;
  int tx = tid & 15;    // n group: cols tx*4..+3
  int ty = tid >> 4;    // m group: rows ty*8..+7
  int m0 = blockIdx.y * BM;
  int n0 = blockIdx.x * BN;
  float acc[8][4];
  #pragma unroll
  for (int i = 0; i < 8; ++i)
    #pragma unroll
    for (int j = 0; j < 4; ++j) acc[i][j] = 0.f;

  const int lkA = tid & 15;   // k for A load
  const int lmA = tid >> 4;   // m base for A load
  const int lnB = tid & 63;
  const int lkB = tid >> 6;

  for (int k0 = 0; k0 < K; k0 += BK) {
    #pragma unroll
    for (int r = 0; r < 8; ++r) {
      int ml = r * 16 + lmA;
      int m = m0 + ml;
      float va = 0.f;
      if (m < M) va = A[(size_t)m * K + k0 + lkA];
      As[lkA][ml] = va;
    }
    #pragma unroll
    for (int r = 0; r < 4; ++r) {
      int kk = r * 4 + lkB;
      int n = n0 + lnB;
      float vb = 0.f;
      if (n < N) vb = Bw[(size_t)(k0 + kk) * N + n];
      Bs[kk][lnB] = vb;
    }
    __syncthreads();
    #pragma unroll
    for (int kk = 0; kk < BK; ++kk) {
      const float4 b4 = *(const float4*)(&Bs[kk][tx * 4]);
      const float4 a0 = *(const float4*)(&As[kk][ty * 8]);
      const float4 a1 = *(const float4*)(&As[kk][ty * 8 + 4]);
      const float a[8] = {a0.x, a0.y, a0.z, a0.w, a1.x, a1.y, a1.z, a1.w};
      const float bb[4] = {b4.x, b4.y, b4.z, b4.w};
      #pragma unroll
      for (int i = 0; i < 8; ++i)
        #pragma unroll
        for (int j = 0; j < 4; ++j)
          acc[i][j] = fmaf(a[i], bb[j], acc[i][j]);
    }
    __syncthreads();
  }

  #pragma unroll
  for (int i = 0; i < 8; ++i) {
    int m = m0 + ty * 8 + i;
    if (m >= M) continue;
    #pragma unroll
    for (int j = 0; j < 4; ++j) {
      int n = n0 + tx * 4 + j;
      if (n >= N) continue;
      float v = acc[i][j] + bias[n];
      if (RES) v += Rsrc[(size_t)m * N + n];
      if (ACT == 1) v = v * 0.5f * (1.0f + erff(v * 0.70710678118654752f));
      C[(size_t)m * N + n] = v;
    }
  }
}

// ---------------- attention (flash-style, f32) ----------------
// block: 256 threads = 32 queries x 8 lanes; KV tiles of 64 in LDS.

#define QCH 32
#define KT 64

__global__ __launch_bounds__(256)
void attn_kernel(const float* __restrict__ QKV, float* __restrict__ O,
                 const int* __restrict__ si) {
  int tok = si[0];
  int bh = blockIdx.x;
  int b = bh / NH, h = bh % NH;
  int t0 = blockIdx.y * QCH;
  if (t0 >= tok) return;
  __shared__ float kl[KT][DH + 4];
  __shared__ float vl[KT][DH + 4];
  int tid = threadIdx.x;
  int qi = tid >> 3;
  int l8 = tid & 7;
  int d0 = l8 * 8;
  int t = t0 + qi;
  bool act = (t < tok);
  float q[8];
  #pragma unroll
  for (int i = 0; i < 8; ++i) q[i] = 0.f;
  if (act) {
    const float* qptr = QKV + ((size_t)(b * TMAX + t)) * QSTRIDE + h * DH + d0;
    #pragma unroll
    for (int i = 0; i < 8; ++i) q[i] = qptr[i];
  }
  float m = -1e30f, l = 0.f;
  float o[8];
  #pragma unroll
  for (int i = 0; i < 8; ++i) o[i] = 0.f;

  int c4 = tid & 15;
  int rbase = tid >> 4;

  for (int j0 = 0; j0 < tok; j0 += KT) {
    int jn = min(KT, tok - j0);
    #pragma unroll
    for (int r = 0; r < 4; ++r) {
      int row = r * 16 + rbase;
      if (row < jn) {
        const float4* sk = (const float4*)(QKV + ((size_t)(b * TMAX + j0 + row)) * QSTRIDE + D + h * DH);
        *(float4*)&kl[row][c4 * 4] = sk[c4];
        const float4* sv = (const float4*)(QKV + ((size_t)(b * TMAX + j0 + row)) * QSTRIDE + 2 * D + h * DH);
        *(float4*)&vl[row][c4 * 4] = sv[c4];
      }
    }
    __syncthreads();
    if (act) {
      for (int j = 0; j < jn; ++j) {
        const float4 k0_ = *(const float4*)&kl[j][d0];
        const float4 k1_ = *(const float4*)&kl[j][d0 + 4];
        float p = q[0] * k0_.x + q[1] * k0_.y + q[2] * k0_.z + q[3] * k0_.w
                + q[4] * k1_.x + q[5] * k1_.y + q[6] * k1_.z + q[7] * k1_.w;
        p += __shfl_xor(p, 1, 8);
        p += __shfl_xor(p, 2, 8);
        p += __shfl_xor(p, 4, 8);
        float s = p * SCALE;
        float mn = fmaxf(m, s);
        float co = expf(m - mn);
        float pe = expf(s - mn);
        l = l * co + pe;
        const float4 v0_ = *(const float4*)&vl[j][d0];
        const float4 v1_ = *(const float4*)&vl[j][d0 + 4];
        const float vv[8] = {v0_.x, v0_.y, v0_.z, v0_.w, v1_.x, v1_.y, v1_.z, v1_.w};
        #pragma unroll
        for (int i = 0; i < 8; ++i) o[i] = o[i] * co + pe * vv[i];
        m = mn;
      }
    }
    __syncthreads();
  }
  if (act) {
    float* op = O + ((size_t)(b * TMAX + t)) * D + h * DH + d0;
    #pragma unroll
    for (int i = 0; i < 8; ++i) op[i] = o[i] / l;
  }
}

// cls attention row per (b,h): softmax(q_cls . K^T * SCALE)
__global__ void clsrow_kernel(const float* __restrict__ QKV, float* __restrict__ Pcls,
                              const int* __restrict__ si) {
  int tok = si[0];
  int bh = blockIdx.x; int b = bh / NH, h = bh % NH;
  int tid = threadIdx.x;
  __shared__ float q[DH];
  __shared__ float red[256];
  if (tid < DH) q[tid] = QKV[((size_t)(b * TMAX)) * QSTRIDE + h * DH + tid];
  __syncthreads();
  float sval = -1e30f;
  if (tid < tok) {
    const float* kp = QKV + ((size_t)(b * TMAX) + tid) * QSTRIDE + D + h * DH;
    float a = 0.f;
    #pragma unroll
    for (int dd = 0; dd < DH; ++dd) a = fmaf(q[dd], kp[dd], a);
    sval = a * SCALE;
  }
  red[tid] = sval; __syncthreads();
  #pragma unroll
  for (int o = 128; o > 0; o >>= 1) { if (tid < o) red[tid] = fmaxf(red[tid], red[tid + o]); __syncthreads(); }
  float mx = red[0]; __syncthreads();
  float e = (tid < tok) ? expf(sval - mx) : 0.f;
  red[tid] = e; __syncthreads();
  #pragma unroll
  for (int o = 128; o > 0; o >>= 1) { if (tid < o) red[tid] += red[tid + o]; __syncthreads(); }
  if (tid < tok) Pcls[(size_t)bh * TMAX + tid] = e / red[0];
}

__global__ void aclsmean_kernel(const float* __restrict__ Pcls, float* __restrict__ Acls,
                                const int* __restrict__ si) {
  int tok = si[0]; int b = blockIdx.x; int tid = threadIdx.x;
  if (tid < tok) {
    float s = 0.f;
    #pragma unroll
    for (int h = 0; h < NH; ++h) s += Pcls[((size_t)b * NH + h) * TMAX + tid];
    Acls[b * TMAX + tid] = s * (1.0f / 12.0f);
  }
}

__global__ void vmean_kernel(const float* __restrict__ QKV, float* __restrict__ Vm,
                             const int* __restrict__ si) {
  int tok = si[0];
  int t = blockIdx.x, b = blockIdx.y;
  if (t >= tok) return;
  int d = threadIdx.x;  // 64
  const float* vp = QKV + ((size_t)(b * TMAX + t)) * QSTRIDE + 2 * D;
  float s = 0.f;
  #pragma unroll
  for (int h = 0; h < NH; ++h) s += vp[h * DH + d];
  Vm[((size_t)b * TMAX + t) * DH + d] = s * (1.0f / 12.0f);
}

// ---------------- pruning stats ----------------

__global__ void stats_kernel(const float* __restrict__ Vm, const float* __restrict__ Acls,
                             float* __restrict__ Jbuf, float* __restrict__ Jsum,
                             float* __restrict__ rhot, const int* __restrict__ si) {
  int tok = si[0]; int N = tok - 1;
  if (N <= 16) return;
  int b = blockIdx.x; int tid = threadIdx.x;
  __shared__ float red[256];
  __shared__ float vmean[DH];
  __shared__ float Vn[NPATCH];
  const float* vb = Vm + (size_t)b * TMAX * DH;

  // rho term: 1 + Acls[b][0] * ||Vm[b,0]||
  float x0 = 0.f;
  if (tid < DH) { float v = vb[tid]; x0 = v * v; }
  red[tid] = x0; __syncthreads();
  #pragma unroll
  for (int o = 128; o > 0; o >>= 1) { if (tid < o) red[tid] += red[tid + o]; __syncthreads(); }
  if (tid == 0) rhot[b] = 1.0f + Acls[b * TMAX] * sqrtf(red[0]);
  __syncthreads();

  // vmean over tokens 1..N
  int d = tid & 63, part = tid >> 6;
  float s = 0.f;
  for (int t = 1 + part; t <= N; t += 4) s += vb[(size_t)t * DH + d];
  red[tid] = s; __syncthreads();
  if (tid < DH) vmean[tid] = (red[tid] + red[tid + 64] + red[tid + 128] + red[tid + 192]) / (float)N;
  __syncthreads();

  // Vn per token
  if (tid < N) {
    const float* vp = vb + (size_t)(tid + 1) * DH;
    float a = 0.f;
    #pragma unroll
    for (int dd = 0; dd < DH; ++dd) { float z = vp[dd] - vmean[dd]; a = fmaf(z, z, a); }
    Vn[tid] = sqrtf(a);
  }
  __syncthreads();

  red[tid] = (tid < N) ? Vn[tid] : 0.f; __syncthreads();
  #pragma unroll
  for (int o = 128; o > 0; o >>= 1) { if (tid < o) red[tid] += red[tid + o]; __syncthreads(); }
  float mu = red[0] / (float)N;
  __syncthreads();
  float dv = (tid < N) ? (Vn[tid] - mu) : 0.f;
  red[tid] = dv * dv; __syncthreads();
  #pragma unroll
  for (int o = 128; o > 0; o >>= 1) { if (tid < o) red[tid] += red[tid + o]; __syncthreads(); }
  float sd = sqrtf(red[0] / (float)(N - 1));
  __syncthreads();

  float Jv = 0.f;
  if (tid < N) {
    float z = (Vn[tid] - mu) / (sd + EPSF);
    z = fmaxf(z, 0.f);
    Jv = Acls[b * TMAX + 1 + tid] * z;
    Jbuf[b * NPATCH + tid] = Jv;
  }
  red[tid] = Jv; __syncthreads();
  #pragma unroll
  for (int o = 128; o > 0; o >>= 1) { if (tid < o) red[tid] += red[tid + o]; __syncthreads(); }
  if (tid == 0) Jsum[b] = red[0];
}

__global__ void decide_kernel(const float* __restrict__ Jbuf, const float* __restrict__ Jsum,
                              const float* __restrict__ rhot, int* __restrict__ keep,
                              int* __restrict__ si, float* __restrict__ sf) {
  int tok = si[0]; int N = tok - 1;
  int tid = threadIdx.x;
  if (N <= 16) { if (tid == 0) si[2] = 0; return; }
  __shared__ float red[256];
  __shared__ float Jms[NPATCH];
  __shared__ int sel[NPATCH];

  red[tid] = (tid < BATCH) ? rhot[tid] : 0.f; __syncthreads();
  #pragma unroll
  for (int o = 128; o > 0; o >>= 1) { if (tid < o) red[tid] += red[tid + o]; __syncthreads(); }
  float rho = red[0] / (float)BATCH; __syncthreads();
  red[tid] = (tid < BATCH) ? Jsum[tid] : 0.f; __syncthreads();
  #pragma unroll
  for (int o = 128; o > 0; o >>= 1) { if (tid < o) red[tid] += red[tid + o]; __syncthreads(); }
  float mass = red[0] / (float)BATCH;
  int prev_valid = si[1];
  float prev = sf[0];
  __syncthreads();

  int N_next = N;
  if (prev_valid) {
    float eta = mass / (prev + EPSF);
    float re = rho * eta;
    re = fminf(fmaxf(re, 0.25f), 4.0f);
    double kr = pow((double)re, -0.01);
    int nn = (int)((double)N * kr);
    N_next = nn > 16 ? nn : 16;
  }
  if (tid == 0) { si[1] = 1; sf[0] = mass; }

  if (N_next < N) {
    if (tid < N) {
      float sJ = 0.f;
      for (int bb = 0; bb < BATCH; ++bb) sJ += Jbuf[bb * NPATCH + tid];
      Jms[tid] = sJ / (float)BATCH;
    }
    __syncthreads();
    if (tid < N) {
      float me = Jms[tid]; int rank = 0;
      for (int s2 = 0; s2 < N; ++s2) {
        float ov = Jms[s2];
        if (ov > me || (ov == me && s2 < tid)) ++rank;
      }
      sel[tid] = (rank < N_next) ? 1 : 0;
    }
    __syncthreads();
    if (tid == 0) {
      int c = 0; keep[c++] = 0;
      for (int t2 = 0; t2 < N; ++t2) if (sel[t2]) keep[c++] = t2 + 1;
      si[0] = N_next + 1;
      si[2] = 1;
    }
  } else {
    if (tid == 0) si[2] = 0;
  }
}

__global__ void gather_kernel(const float* __restrict__ X, float* __restrict__ T,
                              const int* __restrict__ keep, const int* __restrict__ si) {
  if (!si[2]) return;
  int tok = si[0];
  int i = blockIdx.x, b = blockIdx.y;
  if (i >= tok) return;
  int src = keep[i];
  const float* xp = X + ((size_t)(b * TMAX) + src) * D;
  float* tp = T + ((size_t)(b * TMAX) + i) * D;
  int tid = threadIdx.x;
  tp[tid] = xp[tid]; tp[tid + 256] = xp[tid + 256]; tp[tid + 512] = xp[tid + 512];
}

__global__ void copyback_kernel(const float* __restrict__ T, float* __restrict__ X,
                                const int* __restrict__ si) {
  if (!si[2]) return;
  int tok = si[0];
  int i = blockIdx.x, b = blockIdx.y;
  if (i >= tok) return;
  const float* tp = T + ((size_t)(b * TMAX) + i) * D;
  float* xp = X + ((size_t)(b * TMAX) + i) * D;
  int tid = threadIdx.x;
  xp[tid] = tp[tid]; xp[tid + 256] = tp[tid + 256]; xp[tid + 512] = tp[tid + 512];
}

// ---------------- host ----------------

extern "C" void kernel_launch(void* const* d_in, const int* in_sizes, int n_in,
                              void* d_out, int out_size, void* d_ws, size_t ws_size,
                              hipStream_t stream) {
  (void)in_sizes; (void)n_in; (void)out_size;
  const float* x       = (const float*)d_in[0];
  const float* patch_w = (const float*)d_in[1];
  const float* patch_b = (const float*)d_in[2];
  const float* cls_tok = (const float*)d_in[3];
  const float* pos     = (const float*)d_in[4];
  const float* ln1w    = (const float*)d_in[5];
  const float* ln1b    = (const float*)d_in[6];
  const float* qkvw    = (const float*)d_in[7];
  const float* qkvb    = (const float*)d_in[8];
  const float* projw   = (const float*)d_in[9];
  const float* projb   = (const float*)d_in[10];
  const float* ln2w    = (const float*)d_in[11];
  const float* ln2b    = (const float*)d_in[12];
  const float* fc1w    = (const float*)d_in[13];
  const float* fc1b    = (const float*)d_in[14];
  const float* fc2w    = (const float*)d_in[15];
  const float* fc2b    = (const float*)d_in[16];
  const float* normw   = (const float*)d_in[17];
  const float* normb   = (const float*)d_in[18];
  const float* headw   = (const float*)d_in[19];
  const float* headb   = (const float*)d_in[20];
  float* out = (float*)d_out;

  char* w = (char*)d_ws;
  size_t off = 0;
  auto alloc = [&](size_t bytes) -> void* {
    void* p = w + off;
    off += (bytes + 255) & ~(size_t)255;
    return p;
  };
  const size_t MROWS = (size_t)BATCH * TMAX;  // 6304
  float* X    = (float*)alloc(MROWS * D * 4);
  float* XN   = (float*)alloc(MROWS * D * 4);
  float* QKV  = (float*)alloc(MROWS * QSTRIDE * 4);   // also gather TMP
  float* AO   = (float*)alloc(MROWS * D * 4);
  float* H    = (float*)alloc(MROWS * DFF * 4);       // also im2col
  float* Vm   = (float*)alloc(MROWS * DH * 4);
  float* Pcls = (float*)alloc((size_t)BATCH * NH * TMAX * 4);
  float* Acls = (float*)alloc((size_t)BATCH * TMAX * 4);
  float* Jbuf = (float*)alloc((size_t)BATCH * NPATCH * 4);
  float* Jsum = (float*)alloc(BATCH * 4);
  float* rhot = (float*)alloc(BATCH * 4);
  int*   keep = (int*)alloc(256 * 4);
  int*   si   = (int*)alloc(64 * 4);
  float* sf   = (float*)alloc(64 * 4);
  float* CLS  = (float*)alloc((size_t)BATCH * D * 4);
  float* BT   = (float*)alloc((size_t)D * D * 4);
  float* TMP  = QKV;

  if (off > ws_size) {
    fail_kernel<<<1, 1, 0, stream>>>(out);
    return;
  }

  init_kernel<<<1, 1, 0, stream>>>(si, sf);

  // patch embed
  im2col_kernel<<<dim3(NPATCH, BATCH), 256, 0, stream>>>(x, H);
  wtrans_kernel<<<2304, 256, 0, stream>>>(patch_w, BT);
  gemm_kernel<0, 0><<<dim3(12, 49), 256, 0, stream>>>(H, BT, patch_b, nullptr, XN,
                                                      BATCH * NPATCH, D, D);
  assemble_kernel<<<dim3(TMAX, BATCH), 256, 0, stream>>>(XN, cls_tok, pos, X);

  for (int l = 0; l < DEPTH; ++l) {
    const float* l1w = ln1w + l * D;
    const float* l1b = ln1b + l * D;
    const float* qw  = qkvw + (size_t)l * D * 3 * D;
    const float* qb  = qkvb + (size_t)l * 3 * D;
    const float* pw  = projw + (size_t)l * D * D;
    const float* pb  = projb + (size_t)l * D;
    const float* l2w = ln2w + l * D;
    const float* l2b = ln2b + l * D;
    const float* f1w = fc1w + (size_t)l * D * DFF;
    const float* f1b = fc1b + (size_t)l * DFF;
    const float* f2w = fc2w + (size_t)l * DFF * D;
    const float* f2b = fc2b + (size_t)l * D;

    ln_kernel<<<BATCH * TMAX, 256, 0, stream>>>(X, XN, l1w, l1b, si);
    gemm_kernel<0, 0><<<dim3(36, 50), 256, 0, stream>>>(XN, qw, qb, nullptr, QKV,
                                                        BATCH * TMAX, D, 3 * D);
    attn_kernel<<<dim3(BATCH * NH, 7), 256, 0, stream>>>(QKV, AO, si);
    clsrow_kernel<<<BATCH * NH, 256, 0, stream>>>(QKV, Pcls, si);
    aclsmean_kernel<<<BATCH, 256, 0, stream>>>(Pcls, Acls, si);
    vmean_kernel<<<dim3(TMAX, BATCH), 64, 0, stream>>>(QKV, Vm, si);
    gemm_kernel<0, 1><<<dim3(12, 50), 256, 0, stream>>>(AO, pw, pb, X, X,
                                                        BATCH * TMAX, D, D);
    ln_kernel<<<BATCH * TMAX, 256, 0, stream>>>(X, XN, l2w, l2b, si);
    gemm_kernel<1, 0><<<dim3(48, 50), 256, 0, stream>>>(XN, f1w, f1b, nullptr, H,
                                                        BATCH * TMAX, D, DFF);
    gemm_kernel<0, 1><<<dim3(12, 50), 256, 0, stream>>>(H, f2w, f2b, X, X,
                                                        BATCH * TMAX, DFF, D);
    stats_kernel<<<BATCH, 256, 0, stream>>>(Vm, Acls, Jbuf, Jsum, rhot, si);
    decide_kernel<<<1, 256, 0, stream>>>(Jbuf, Jsum, rhot, keep, si, sf);
    gather_kernel<<<dim3(TMAX, BATCH), 256, 0, stream>>>(X, TMP, keep, si);
    copyback_kernel<<<dim3(TMAX, BATCH), 256, 0, stream>>>(TMP, X, si);
  }

  lnfinal_kernel<<<BATCH, 256, 0, stream>>>(X, CLS, normw, normb);
  gemm_kernel<0, 0><<<dim3(16, 1), 256, 0, stream>>>(CLS, headw, headb, nullptr, out,
                                                     BATCH, D, NC);
}

// Round 2
// 8367.619 us; speedup vs baseline: 2.8917x; 2.8917x over previous
//
#include <hip/hip_runtime.h>
#include <math.h>

#define D 768
#define NH 12
#define DH 64
#define DEPTH 12
#define TMAX 197
#define NPATCH 196
#define BATCH 32
#define DFF 3072
#define NC 1000
#define QSTRIDE 2304   // 3*D
#define SCALE 0.125f
#define EPSF 1e-6f

typedef __bf16 bf16x8 __attribute__((ext_vector_type(8)));
typedef float f32x4 __attribute__((ext_vector_type(4)));

// ---------------- bf16 split helpers ----------------

__device__ __forceinline__ short f2bf(float x) {
  unsigned u = __float_as_uint(x);
  u = u + 0x7fffu + ((u >> 16) & 1u);
  return (short)(u >> 16);
}
__device__ __forceinline__ float bf2f(short h) {
  return __uint_as_float(((unsigned)(unsigned short)h) << 16);
}
__device__ __forceinline__ void bsplit(float x, short* hp, short* lp) {
  short h = f2bf(x);
  *hp = h;
  *lp = f2bf(x - bf2f(h));
}

// global -> LDS direct copy, 16B per lane. LDS dest must be wave-uniform base.
__device__ __forceinline__ void gll16(const void* g, void* l) {
  __builtin_amdgcn_global_load_lds(
      (const __attribute__((address_space(1))) void*)g,
      (__attribute__((address_space(3))) void*)l, 16, 0, 0);
}

// ---------------- utility ----------------

__device__ __forceinline__ float block_reduce_sum(float v, float* red, int tid) {
  red[tid] = v; __syncthreads();
  #pragma unroll
  for (int o = 128; o > 0; o >>= 1) { if (tid < o) red[tid] += red[tid + o]; __syncthreads(); }
  float r = red[0]; __syncthreads();
  return r;
}

__global__ void fail_kernel(float* out) { out[0] = 1.0e6f; }

__global__ void init_kernel(int* si, float* sf) {
  si[0] = TMAX;  // tok (N+1)
  si[1] = 0;     // prev_mass valid
  si[2] = 0;     // prune flag this layer
  sf[0] = 0.f;   // prev_mass
}

// ---------------- weight split/transpose ----------------
// W f32 [K][N] -> Wpk bf16 [N][2][K]  (hi plane, lo plane; k contiguous)
__global__ void wsplit_t(const float* __restrict__ W, short* __restrict__ Wpk,
                         int K, int N) {
  __shared__ float t[32][33];
  int n0 = blockIdx.x * 32, k0 = blockIdx.y * 32;
  int tid = threadIdx.x;
  int kk = tid >> 3, n4 = (tid & 7) * 4;
  float4 v = *(const float4*)(W + (size_t)(k0 + kk) * N + n0 + n4);
  t[kk][n4] = v.x; t[kk][n4 + 1] = v.y; t[kk][n4 + 2] = v.z; t[kk][n4 + 3] = v.w;
  __syncthreads();
  int nn = tid >> 3, k4 = (tid & 7) * 4;
  short* dh = Wpk + (size_t)(n0 + nn) * 2 * K + k0 + k4;
  short* dl = dh + K;
  #pragma unroll
  for (int c = 0; c < 4; ++c) bsplit(t[k4 + c][nn], &dh[c], &dl[c]);
}

// W f32 [N][K] (already k-contiguous) -> Wpk [N][2][K]
__global__ void wsplit_nt(const float* __restrict__ W, short* __restrict__ Wpk, int K) {
  const float* src = W + (size_t)blockIdx.x * K;
  short* dh = Wpk + (size_t)blockIdx.x * 2 * K;
  short* dl = dh + K;
  for (int k = threadIdx.x; k < K; k += 256) bsplit(src[k], &dh[k], &dl[k]);
}

// ---------------- embed ----------------

__global__ void im2col_kernel(const float* __restrict__ x, short* __restrict__ Impk) {
  int p = blockIdx.x, b = blockIdx.y;
  int py = p / 14, px = p % 14;
  short* dst = Impk + ((size_t)b * NPATCH + p) * 1536;
  for (int k = threadIdx.x; k < D; k += 256) {
    int c = k >> 8; int rem = k & 255; int i = rem >> 4; int j = rem & 15;
    float v = x[(((size_t)b * 3 + c) * 224 + py * 16 + i) * 224 + px * 16 + j];
    bsplit(v, &dst[k], &dst[768 + k]);
  }
}

__global__ void assemble_kernel(const float* __restrict__ PE, const float* __restrict__ cls,
                                const float* __restrict__ pos, float* __restrict__ X) {
  int t = blockIdx.x, b = blockIdx.y; int tid = threadIdx.x;
  float* xp = X + ((size_t)(b * TMAX) + t) * D;
  for (int k = tid; k < D; k += 256) {
    float v = (t == 0) ? cls[k] : PE[((size_t)(b * NPATCH) + (t - 1)) * D + k];
    xp[k] = v + pos[(size_t)t * D + k];
  }
}

// ---------------- layernorm ----------------

__global__ void ln_kernel(const float* __restrict__ Xin, short* __restrict__ XNpk,
                          const float* __restrict__ wgt, const float* __restrict__ bsh,
                          const int* __restrict__ si) {
  int row = blockIdx.x;
  if ((row % TMAX) >= si[0]) return;
  __shared__ float red[256];
  int tid = threadIdx.x;
  const float* xp = Xin + (size_t)row * D;
  float v0 = xp[tid], v1 = xp[tid + 256], v2 = xp[tid + 512];
  float mu = block_reduce_sum(v0 + v1 + v2, red, tid) * (1.0f / 768.0f);
  float d0 = v0 - mu, d1 = v1 - mu, d2 = v2 - mu;
  float var = block_reduce_sum(d0 * d0 + d1 * d1 + d2 * d2, red, tid) * (1.0f / 768.0f);
  float inv = 1.0f / sqrtf(var + EPSF);
  short* op = XNpk + (size_t)row * 1536;
  float y0 = d0 * inv * wgt[tid] + bsh[tid];
  float y1 = d1 * inv * wgt[tid + 256] + bsh[tid + 256];
  float y2 = d2 * inv * wgt[tid + 512] + bsh[tid + 512];
  bsplit(y0, &op[tid], &op[768 + tid]);
  bsplit(y1, &op[tid + 256], &op[768 + tid + 256]);
  bsplit(y2, &op[tid + 512], &op[768 + tid + 512]);
}

__global__ void lnfinal_kernel(const float* __restrict__ X, float* __restrict__ CLSb,
                               const float* __restrict__ wgt, const float* __restrict__ bsh) {
  int b = blockIdx.x; int tid = threadIdx.x;
  __shared__ float red[256];
  const float* xp = X + (size_t)b * TMAX * D;  // row t=0
  float v0 = xp[tid], v1 = xp[tid + 256], v2 = xp[tid + 512];
  float mu = block_reduce_sum(v0 + v1 + v2, red, tid) * (1.0f / 768.0f);
  float d0 = v0 - mu, d1 = v1 - mu, d2 = v2 - mu;
  float var = block_reduce_sum(d0 * d0 + d1 * d1 + d2 * d2, red, tid) * (1.0f / 768.0f);
  float inv = 1.0f / sqrtf(var + EPSF);
  float* op = CLSb + (size_t)b * D;
  op[tid]       = d0 * inv * wgt[tid]       + bsh[tid];
  op[tid + 256] = d1 * inv * wgt[tid + 256] + bsh[tid + 256];
  op[tid + 512] = d2 * inv * wgt[tid + 512] + bsh[tid + 512];
}

// ---------------- MFMA GEMM (bf16x3 split emulation of f32) ----------------
// C[M,N] = epi(A @ W + bias [+ Rsrc]) with A = Apk [M][2][K] bf16 hi/lo,
// W given as Bpk [N][2][K] bf16 hi/lo (k-contiguous).
// 128x128 tile, 256 threads = 4 waves (2x2), each wave 64x64 via 4x4 frags of
// mfma_f32_16x16x32_bf16, 3 MFMAs per frag pair (hihi, hilo, lohi).
// LDS row = 128B: [hi 4 slots][lo 4 slots] of 16B; slot XOR-swizzled with row&7.
// Staged by global_load_lds (linear dest, inverse-swizzled source).

#define GTM 128
#define GTN 128
#define GTK 32

template<int EPI>
__global__ __launch_bounds__(256)
void mgemm_kernel(const short* __restrict__ Apk, const short* __restrict__ Bpk,
                  const float* __restrict__ bias, const float* __restrict__ Rsrc,
                  float* __restrict__ Cf, short* __restrict__ Cpk,
                  int M, int K, int N) {
  __shared__ char lds[65536];  // 2 buffers x (A 16KB | B 16KB)
  const int tid = threadIdx.x;
  const int ln = tid & 63;
  const int wv = tid >> 6;
  const int wm = wv >> 1, wn = wv & 1;
  const int m0 = blockIdx.y * GTM, n0 = blockIdx.x * GTN;
  const int lm = ln & 15, kc = ln >> 4;
  const size_t rs = 2 * (size_t)K;

  f32x4 acc[4][4];
  f32x4 zv = {0.f, 0.f, 0.f, 0.f};
  #pragma unroll
  for (int i = 0; i < 4; ++i)
    #pragma unroll
    for (int j = 0; j < 4; ++j) acc[i][j] = zv;

  auto stage = [&](int k0, int buf) {
    char* base = lds + (buf << 15);
    #pragma unroll
    for (int i = 0; i < 4; ++i) {
      int s = (i << 8) + tid;          // physical 16B slot index
      int r = s >> 3;                  // row 0..127
      int sl = (s & 7) ^ (r & 7);      // logical slot (inverse swizzle)
      size_t eoff = (size_t)(sl >> 2) * K + (size_t)(k0 + ((sl & 3) << 3));
      int ldsoff = ((i << 8) + (tid & 192)) << 4;  // wave-uniform
      gll16(Apk + (size_t)(m0 + r) * rs + eoff, base + ldsoff);
      gll16(Bpk + (size_t)(n0 + r) * rs + eoff, base + 16384 + ldsoff);
    }
  };

  const int nk = K / GTK;
  stage(0, 0);
  for (int kt = 0; kt < nk; ++kt) {
    __syncthreads();                    // drains vmcnt -> staged tile visible
    if (kt + 1 < nk) stage((kt + 1) * GTK, (kt + 1) & 1);
    const char* pa = lds + ((kt & 1) << 15);
    const char* pb = pa + 16384;
    bf16x8 bh[4], bl[4];
    #pragma unroll
    for (int j = 0; j < 4; ++j) {
      int c = wn * 64 + j * 16 + lm;
      int bo = c * 128 + ((kc ^ (c & 7)) << 4);
      bh[j] = *(const bf16x8*)(pb + bo);
      bl[j] = *(const bf16x8*)(pb + (bo ^ 64));
    }
    #pragma unroll
    for (int i = 0; i < 4; ++i) {
      int r = wm * 64 + i * 16 + lm;
      int ao = r * 128 + ((kc ^ (r & 7)) << 4);
      bf16x8 ah = *(const bf16x8*)(pa + ao);
      bf16x8 al = *(const bf16x8*)(pa + (ao ^ 64));
      #pragma unroll
      for (int j = 0; j < 4; ++j) {
        acc[i][j] = __builtin_amdgcn_mfma_f32_16x16x32_bf16(ah, bh[j], acc[i][j], 0, 0, 0);
        acc[i][j] = __builtin_amdgcn_mfma_f32_16x16x32_bf16(ah, bl[j], acc[i][j], 0, 0, 0);
        acc[i][j] = __builtin_amdgcn_mfma_f32_16x16x32_bf16(al, bh[j], acc[i][j], 0, 0, 0);
      }
    }
  }

  // epilogue: C/D layout col = ln&15, row = (ln>>4)*4 + t
  #pragma unroll
  for (int i = 0; i < 4; ++i) {
    #pragma unroll
    for (int t = 0; t < 4; ++t) {
      int m = m0 + wm * 64 + i * 16 + kc * 4 + t;
      if (m >= M) continue;
      #pragma unroll
      for (int j = 0; j < 4; ++j) {
        int n = n0 + wn * 64 + j * 16 + lm;
        float v = acc[i][j][t] + bias[n];
        if (EPI == 1) v += Rsrc[(size_t)m * N + n];
        if (EPI == 2) {
          v = v * 0.5f * (1.0f + erff(v * 0.70710678118654752f));
          short h = f2bf(v);
          Cpk[(size_t)m * 2 * N + n] = h;
          Cpk[(size_t)m * 2 * N + N + n] = f2bf(v - bf2f(h));
        } else {
          Cf[(size_t)m * N + n] = v;
        }
      }
    }
  }
}

// ---------------- f32 GEMM (head only) ----------------

#define BM 128
#define BN 64
#define BK 16

__global__ __launch_bounds__(256, 2)
void gemm_kernel(const float* __restrict__ A, const float* __restrict__ Bw,
                 const float* __restrict__ bias, float* __restrict__ C,
                 int M, int K, int N) {
  __shared__ float As[BK][BM + 4];
  __shared__ float Bs[BK][BN];
  int tid = threadIdx.x;
  int tx = tid & 15;
  int ty = tid >> 4;
  int m0 = blockIdx.y * BM;
  int n0 = blockIdx.x * BN;
  float acc[8][4];
  #pragma unroll
  for (int i = 0; i < 8; ++i)
    #pragma unroll
    for (int j = 0; j < 4; ++j) acc[i][j] = 0.f;
  const int lkA = tid & 15;
  const int lmA = tid >> 4;
  const int lnB = tid & 63;
  const int lkB = tid >> 6;
  for (int k0 = 0; k0 < K; k0 += BK) {
    #pragma unroll
    for (int r = 0; r < 8; ++r) {
      int ml = r * 16 + lmA;
      int m = m0 + ml;
      float va = 0.f;
      if (m < M) va = A[(size_t)m * K + k0 + lkA];
      As[lkA][ml] = va;
    }
    #pragma unroll
    for (int r = 0; r < 4; ++r) {
      int kk = r * 4 + lkB;
      int n = n0 + lnB;
      float vb = 0.f;
      if (n < N) vb = Bw[(size_t)(k0 + kk) * N + n];
      Bs[kk][lnB] = vb;
    }
    __syncthreads();
    #pragma unroll
    for (int kk = 0; kk < BK; ++kk) {
      const float4 b4 = *(const float4*)(&Bs[kk][tx * 4]);
      const float4 a0 = *(const float4*)(&As[kk][ty * 8]);
      const float4 a1 = *(const float4*)(&As[kk][ty * 8 + 4]);
      const float a[8] = {a0.x, a0.y, a0.z, a0.w, a1.x, a1.y, a1.z, a1.w};
      const float bb[4] = {b4.x, b4.y, b4.z, b4.w};
      #pragma unroll
      for (int i = 0; i < 8; ++i)
        #pragma unroll
        for (int j = 0; j < 4; ++j)
          acc[i][j] = fmaf(a[i], bb[j], acc[i][j]);
    }
    __syncthreads();
  }
  #pragma unroll
  for (int i = 0; i < 8; ++i) {
    int m = m0 + ty * 8 + i;
    if (m >= M) continue;
    #pragma unroll
    for (int j = 0; j < 4; ++j) {
      int n = n0 + tx * 4 + j;
      if (n >= N) continue;
      C[(size_t)m * N + n] = acc[i][j] + bias[n];
    }
  }
}

// ---------------- attention (flash-style, f32) ----------------

#define QCH 32
#define KT 64

__global__ __launch_bounds__(256)
void attn_kernel(const float* __restrict__ QKV, short* __restrict__ AOpk,
                 const int* __restrict__ si) {
  int tok = si[0];
  int bh = blockIdx.x;
  int b = bh / NH, h = bh % NH;
  int t0 = blockIdx.y * QCH;
  if (t0 >= tok) return;
  __shared__ float kl[KT][DH + 4];
  __shared__ float vl[KT][DH + 4];
  int tid = threadIdx.x;
  int qi = tid >> 3;
  int l8 = tid & 7;
  int d0 = l8 * 8;
  int t = t0 + qi;
  bool act = (t < tok);
  float q[8];
  #pragma unroll
  for (int i = 0; i < 8; ++i) q[i] = 0.f;
  if (act) {
    const float* qptr = QKV + ((size_t)(b * TMAX + t)) * QSTRIDE + h * DH + d0;
    #pragma unroll
    for (int i = 0; i < 8; ++i) q[i] = qptr[i];
  }
  float m = -1e30f, l = 0.f;
  float o[8];
  #pragma unroll
  for (int i = 0; i < 8; ++i) o[i] = 0.f;

  int c4 = tid & 15;
  int rbase = tid >> 4;

  for (int j0 = 0; j0 < tok; j0 += KT) {
    int jn = min(KT, tok - j0);
    #pragma unroll
    for (int r = 0; r < 4; ++r) {
      int row = r * 16 + rbase;
      if (row < jn) {
        const float4* sk = (const float4*)(QKV + ((size_t)(b * TMAX + j0 + row)) * QSTRIDE + D + h * DH);
        *(float4*)&kl[row][c4 * 4] = sk[c4];
        const float4* sv = (const float4*)(QKV + ((size_t)(b * TMAX + j0 + row)) * QSTRIDE + 2 * D + h * DH);
        *(float4*)&vl[row][c4 * 4] = sv[c4];
      }
    }
    __syncthreads();
    if (act) {
      for (int j = 0; j < jn; ++j) {
        const float4 k0_ = *(const float4*)&kl[j][d0];
        const float4 k1_ = *(const float4*)&kl[j][d0 + 4];
        float p = q[0] * k0_.x + q[1] * k0_.y + q[2] * k0_.z + q[3] * k0_.w
                + q[4] * k1_.x + q[5] * k1_.y + q[6] * k1_.z + q[7] * k1_.w;
        p += __shfl_xor(p, 1, 8);
        p += __shfl_xor(p, 2, 8);
        p += __shfl_xor(p, 4, 8);
        float s = p * SCALE;
        float mn = fmaxf(m, s);
        float co = expf(m - mn);
        float pe = expf(s - mn);
        l = l * co + pe;
        const float4 v0_ = *(const float4*)&vl[j][d0];
        const float4 v1_ = *(const float4*)&vl[j][d0 + 4];
        const float vv[8] = {v0_.x, v0_.y, v0_.z, v0_.w, v1_.x, v1_.y, v1_.z, v1_.w};
        #pragma unroll
        for (int i = 0; i < 8; ++i) o[i] = o[i] * co + pe * vv[i];
        m = mn;
      }
    }
    __syncthreads();
  }
  if (act) {
    short* op = AOpk + (size_t)(b * TMAX + t) * 1536 + h * DH + d0;
    #pragma unroll
    for (int i = 0; i < 8; ++i) {
      float y = o[i] / l;
      bsplit(y, &op[i], &op[768 + i]);
    }
  }
}

// cls attention row per (b,h)
__global__ void clsrow_kernel(const float* __restrict__ QKV, float* __restrict__ Pcls,
                              const int* __restrict__ si) {
  int tok = si[0];
  int bh = blockIdx.x; int b = bh / NH, h = bh % NH;
  int tid = threadIdx.x;
  __shared__ float q[DH];
  __shared__ float red[256];
  if (tid < DH) q[tid] = QKV[((size_t)(b * TMAX)) * QSTRIDE + h * DH + tid];
  __syncthreads();
  float sval = -1e30f;
  if (tid < tok) {
    const float* kp = QKV + ((size_t)(b * TMAX) + tid) * QSTRIDE + D + h * DH;
    float a = 0.f;
    #pragma unroll
    for (int dd = 0; dd < DH; ++dd) a = fmaf(q[dd], kp[dd], a);
    sval = a * SCALE;
  }
  red[tid] = sval; __syncthreads();
  #pragma unroll
  for (int o = 128; o > 0; o >>= 1) { if (tid < o) red[tid] = fmaxf(red[tid], red[tid + o]); __syncthreads(); }
  float mx = red[0]; __syncthreads();
  float e = (tid < tok) ? expf(sval - mx) : 0.f;
  red[tid] = e; __syncthreads();
  #pragma unroll
  for (int o = 128; o > 0; o >>= 1) { if (tid < o) red[tid] += red[tid + o]; __syncthreads(); }
  if (tid < tok) Pcls[(size_t)bh * TMAX + tid] = e / red[0];
}

__global__ void aclsmean_kernel(const float* __restrict__ Pcls, float* __restrict__ Acls,
                                const int* __restrict__ si) {
  int tok = si[0]; int b = blockIdx.x; int tid = threadIdx.x;
  if (tid < tok) {
    float s = 0.f;
    #pragma unroll
    for (int h = 0; h < NH; ++h) s += Pcls[((size_t)b * NH + h) * TMAX + tid];
    Acls[b * TMAX + tid] = s * (1.0f / 12.0f);
  }
}

__global__ void vmean_kernel(const float* __restrict__ QKV, float* __restrict__ Vm,
                             const int* __restrict__ si) {
  int tok = si[0];
  int t = blockIdx.x, b = blockIdx.y;
  if (t >= tok) return;
  int d = threadIdx.x;  // 64
  const float* vp = QKV + ((size_t)(b * TMAX + t)) * QSTRIDE + 2 * D;
  float s = 0.f;
  #pragma unroll
  for (int h = 0; h < NH; ++h) s += vp[h * DH + d];
  Vm[((size_t)b * TMAX + t) * DH + d] = s * (1.0f / 12.0f);
}

// ---------------- pruning stats ----------------

__global__ void stats_kernel(const float* __restrict__ Vm, const float* __restrict__ Acls,
                             float* __restrict__ Jbuf, float* __restrict__ Jsum,
                             float* __restrict__ rhot, const int* __restrict__ si) {
  int tok = si[0]; int N = tok - 1;
  if (N <= 16) return;
  int b = blockIdx.x; int tid = threadIdx.x;
  __shared__ float red[256];
  __shared__ float vmean[DH];
  __shared__ float Vn[NPATCH];
  const float* vb = Vm + (size_t)b * TMAX * DH;

  float x0 = 0.f;
  if (tid < DH) { float v = vb[tid]; x0 = v * v; }
  red[tid] = x0; __syncthreads();
  #pragma unroll
  for (int o = 128; o > 0; o >>= 1) { if (tid < o) red[tid] += red[tid + o]; __syncthreads(); }
  if (tid == 0) rhot[b] = 1.0f + Acls[b * TMAX] * sqrtf(red[0]);
  __syncthreads();

  int d = tid & 63, part = tid >> 6;
  float s = 0.f;
  for (int t = 1 + part; t <= N; t += 4) s += vb[(size_t)t * DH + d];
  red[tid] = s; __syncthreads();
  if (tid < DH) vmean[tid] = (red[tid] + red[tid + 64] + red[tid + 128] + red[tid + 192]) / (float)N;
  __syncthreads();

  if (tid < N) {
    const float* vp = vb + (size_t)(tid + 1) * DH;
    float a = 0.f;
    #pragma unroll
    for (int dd = 0; dd < DH; ++dd) { float z = vp[dd] - vmean[dd]; a = fmaf(z, z, a); }
    Vn[tid] = sqrtf(a);
  }
  __syncthreads();

  red[tid] = (tid < N) ? Vn[tid] : 0.f; __syncthreads();
  #pragma unroll
  for (int o = 128; o > 0; o >>= 1) { if (tid < o) red[tid] += red[tid + o]; __syncthreads(); }
  float mu = red[0] / (float)N;
  __syncthreads();
  float dv = (tid < N) ? (Vn[tid] - mu) : 0.f;
  red[tid] = dv * dv; __syncthreads();
  #pragma unroll
  for (int o = 128; o > 0; o >>= 1) { if (tid < o) red[tid] += red[tid + o]; __syncthreads(); }
  float sd = sqrtf(red[0] / (float)(N - 1));
  __syncthreads();

  float Jv = 0.f;
  if (tid < N) {
    float z = (Vn[tid] - mu) / (sd + EPSF);
    z = fmaxf(z, 0.f);
    Jv = Acls[b * TMAX + 1 + tid] * z;
    Jbuf[b * NPATCH + tid] = Jv;
  }
  red[tid] = Jv; __syncthreads();
  #pragma unroll
  for (int o = 128; o > 0; o >>= 1) { if (tid < o) red[tid] += red[tid + o]; __syncthreads(); }
  if (tid == 0) Jsum[b] = red[0];
}

__global__ void decide_kernel(const float* __restrict__ Jbuf, const float* __restrict__ Jsum,
                              const float* __restrict__ rhot, int* __restrict__ keep,
                              int* __restrict__ si, float* __restrict__ sf) {
  int tok = si[0]; int N = tok - 1;
  int tid = threadIdx.x;
  if (N <= 16) { if (tid == 0) si[2] = 0; return; }
  __shared__ float red[256];
  __shared__ float Jms[NPATCH];
  __shared__ int sel[NPATCH];

  red[tid] = (tid < BATCH) ? rhot[tid] : 0.f; __syncthreads();
  #pragma unroll
  for (int o = 128; o > 0; o >>= 1) { if (tid < o) red[tid] += red[tid + o]; __syncthreads(); }
  float rho = red[0] / (float)BATCH; __syncthreads();
  red[tid] = (tid < BATCH) ? Jsum[tid] : 0.f; __syncthreads();
  #pragma unroll
  for (int o = 128; o > 0; o >>= 1) { if (tid < o) red[tid] += red[tid + o]; __syncthreads(); }
  float mass = red[0] / (float)BATCH;
  int prev_valid = si[1];
  float prev = sf[0];
  __syncthreads();

  int N_next = N;
  if (prev_valid) {
    float eta = mass / (prev + EPSF);
    float re = rho * eta;
    re = fminf(fmaxf(re, 0.25f), 4.0f);
    double kr = pow((double)re, -0.01);
    int nn = (int)((double)N * kr);
    N_next = nn > 16 ? nn : 16;
  }
  if (tid == 0) { si[1] = 1; sf[0] = mass; }

  if (N_next < N) {
    if (tid < N) {
      float sJ = 0.f;
      for (int bb = 0; bb < BATCH; ++bb) sJ += Jbuf[bb * NPATCH + tid];
      Jms[tid] = sJ / (float)BATCH;
    }
    __syncthreads();
    if (tid < N) {
      float me = Jms[tid]; int rank = 0;
      for (int s2 = 0; s2 < N; ++s2) {
        float ov = Jms[s2];
        if (ov > me || (ov == me && s2 < tid)) ++rank;
      }
      sel[tid] = (rank < N_next) ? 1 : 0;
    }
    __syncthreads();
    if (tid == 0) {
      int c = 0; keep[c++] = 0;
      for (int t2 = 0; t2 < N; ++t2) if (sel[t2]) keep[c++] = t2 + 1;
      si[0] = N_next + 1;
      si[2] = 1;
    }
  } else {
    if (tid == 0) si[2] = 0;
  }
}

__global__ void gather_kernel(const float* __restrict__ X, float* __restrict__ T,
                              const int* __restrict__ keep, const int* __restrict__ si) {
  if (!si[2]) return;
  int tok = si[0];
  int i = blockIdx.x, b = blockIdx.y;
  if (i >= tok) return;
  int src = keep[i];
  const float* xp = X + ((size_t)(b * TMAX) + src) * D;
  float* tp = T + ((size_t)(b * TMAX) + i) * D;
  int tid = threadIdx.x;
  tp[tid] = xp[tid]; tp[tid + 256] = xp[tid + 256]; tp[tid + 512] = xp[tid + 512];
}

__global__ void copyback_kernel(const float* __restrict__ T, float* __restrict__ X,
                                const int* __restrict__ si) {
  if (!si[2]) return;
  int tok = si[0];
  int i = blockIdx.x, b = blockIdx.y;
  if (i >= tok) return;
  const float* tp = T + ((size_t)(b * TMAX) + i) * D;
  float* xp = X + ((size_t)(b * TMAX) + i) * D;
  int tid = threadIdx.x;
  xp[tid] = tp[tid]; xp[tid + 256] = tp[tid + 256]; xp[tid + 512] = tp[tid + 512];
}

// ---------------- host ----------------

extern "C" void kernel_launch(void* const* d_in, const int* in_sizes, int n_in,
                              void* d_out, int out_size, void* d_ws, size_t ws_size,
                              hipStream_t stream) {
  (void)in_sizes; (void)n_in; (void)out_size;
  const float* x       = (const float*)d_in[0];
  const float* patch_w = (const float*)d_in[1];
  const float* patch_b = (const float*)d_in[2];
  const float* cls_tok = (const float*)d_in[3];
  const float* pos     = (const float*)d_in[4];
  const float* ln1w    = (const float*)d_in[5];
  const float* ln1b    = (const float*)d_in[6];
  const float* qkvw    = (const float*)d_in[7];
  const float* qkvb    = (const float*)d_in[8];
  const float* projw   = (const float*)d_in[9];
  const float* projb   = (const float*)d_in[10];
  const float* ln2w    = (const float*)d_in[11];
  const float* ln2b    = (const float*)d_in[12];
  const float* fc1w    = (const float*)d_in[13];
  const float* fc1b    = (const float*)d_in[14];
  const float* fc2w    = (const float*)d_in[15];
  const float* fc2b    = (const float*)d_in[16];
  const float* normw   = (const float*)d_in[17];
  const float* normb   = (const float*)d_in[18];
  const float* headw   = (const float*)d_in[19];
  const float* headb   = (const float*)d_in[20];
  float* out = (float*)d_out;

  char* w = (char*)d_ws;
  size_t off = 0;
  auto alloc = [&](size_t bytes) -> void* {
    void* p = w + off;
    off += (bytes + 255) & ~(size_t)255;
    return p;
  };
  const size_t MROWS = (size_t)BATCH * TMAX;  // 6304
  float* X    = (float*)alloc(MROWS * D * 4);
  short* XNpk = (short*)alloc(MROWS * 1536 * 2);
  float* QKV  = (float*)alloc(MROWS * QSTRIDE * 4);   // also embed f32 out
  short* AOpk = (short*)alloc(MROWS * 1536 * 2);
  short* Hpk  = (short*)alloc(MROWS * 2 * DFF * 2);   // also Impk / gather TMP
  float* Vm   = (float*)alloc(MROWS * DH * 4);
  float* Pcls = (float*)alloc((size_t)BATCH * NH * TMAX * 4);
  float* Acls = (float*)alloc((size_t)BATCH * TMAX * 4);
  float* Jbuf = (float*)alloc((size_t)BATCH * NPATCH * 4);
  float* Jsum = (float*)alloc(BATCH * 4);
  float* rhot = (float*)alloc(BATCH * 4);
  int*   keep = (int*)alloc(256 * 4);
  int*   si   = (int*)alloc(64 * 4);
  float* sf   = (float*)alloc(64 * 4);
  float* CLS  = (float*)alloc((size_t)BATCH * D * 4);
  short* Wq   = (short*)alloc((size_t)QSTRIDE * 2 * D * 2);
  short* Wp   = (short*)alloc((size_t)D * 2 * D * 2);
  short* W1   = (short*)alloc((size_t)DFF * 2 * D * 2);
  short* W2   = (short*)alloc((size_t)D * 2 * DFF * 2);
  short* Wpat = (short*)alloc((size_t)D * 2 * D * 2);
  short* Impk = Hpk;
  float* TMP  = (float*)Hpk;
  float* Ef32 = QKV;

  if (off > ws_size) {
    fail_kernel<<<1, 1, 0, stream>>>(out);
    return;
  }

  init_kernel<<<1, 1, 0, stream>>>(si, sf);

  // patch embed
  im2col_kernel<<<dim3(NPATCH, BATCH), 256, 0, stream>>>(x, Impk);
  wsplit_nt<<<D, 256, 0, stream>>>(patch_w, Wpat, D);
  mgemm_kernel<0><<<dim3(D / GTN, (BATCH * NPATCH + GTM - 1) / GTM), 256, 0, stream>>>(
      Impk, Wpat, patch_b, nullptr, Ef32, nullptr, BATCH * NPATCH, D, D);
  assemble_kernel<<<dim3(TMAX, BATCH), 256, 0, stream>>>(Ef32, cls_tok, pos, X);

  const int MG = (int)((MROWS + GTM - 1) / GTM);  // 50

  for (int l = 0; l < DEPTH; ++l) {
    const float* l1w = ln1w + l * D;
    const float* l1b = ln1b + l * D;
    const float* qw  = qkvw + (size_t)l * D * 3 * D;
    const float* qb  = qkvb + (size_t)l * 3 * D;
    const float* pw  = projw + (size_t)l * D * D;
    const float* pb  = projb + (size_t)l * D;
    const float* l2w = ln2w + l * D;
    const float* l2b = ln2b + l * D;
    const float* f1w = fc1w + (size_t)l * D * DFF;
    const float* f1b = fc1b + (size_t)l * DFF;
    const float* f2w = fc2w + (size_t)l * DFF * D;
    const float* f2b = fc2b + (size_t)l * D;

    wsplit_t<<<dim3(QSTRIDE / 32, D / 32), 256, 0, stream>>>(qw, Wq, D, QSTRIDE);
    wsplit_t<<<dim3(D / 32, D / 32), 256, 0, stream>>>(pw, Wp, D, D);
    wsplit_t<<<dim3(DFF / 32, D / 32), 256, 0, stream>>>(f1w, W1, D, DFF);
    wsplit_t<<<dim3(D / 32, DFF / 32), 256, 0, stream>>>(f2w, W2, DFF, D);

    ln_kernel<<<BATCH * TMAX, 256, 0, stream>>>(X, XNpk, l1w, l1b, si);
    mgemm_kernel<0><<<dim3(QSTRIDE / GTN, MG), 256, 0, stream>>>(
        XNpk, Wq, qb, nullptr, QKV, nullptr, (int)MROWS, D, QSTRIDE);
    attn_kernel<<<dim3(BATCH * NH, 7), 256, 0, stream>>>(QKV, AOpk, si);
    clsrow_kernel<<<BATCH * NH, 256, 0, stream>>>(QKV, Pcls, si);
    aclsmean_kernel<<<BATCH, 256, 0, stream>>>(Pcls, Acls, si);
    vmean_kernel<<<dim3(TMAX, BATCH), 64, 0, stream>>>(QKV, Vm, si);
    mgemm_kernel<1><<<dim3(D / GTN, MG), 256, 0, stream>>>(
        AOpk, Wp, pb, X, X, nullptr, (int)MROWS, D, D);
    ln_kernel<<<BATCH * TMAX, 256, 0, stream>>>(X, XNpk, l2w, l2b, si);
    mgemm_kernel<2><<<dim3(DFF / GTN, MG), 256, 0, stream>>>(
        XNpk, W1, f1b, nullptr, nullptr, Hpk, (int)MROWS, D, DFF);
    mgemm_kernel<1><<<dim3(D / GTN, MG), 256, 0, stream>>>(
        Hpk, W2, f2b, X, X, nullptr, (int)MROWS, DFF, D);
    stats_kernel<<<BATCH, 256, 0, stream>>>(Vm, Acls, Jbuf, Jsum, rhot, si);
    decide_kernel<<<1, 256, 0, stream>>>(Jbuf, Jsum, rhot, keep, si, sf);
    gather_kernel<<<dim3(TMAX, BATCH), 256, 0, stream>>>(X, TMP, keep, si);
    copyback_kernel<<<dim3(TMAX, BATCH), 256, 0, stream>>>(TMP, X, si);
  }

  lnfinal_kernel<<<BATCH, 256, 0, stream>>>(X, CLS, normw, normb);
  gemm_kernel<<<dim3(16, 1), 256, 0, stream>>>(CLS, headw, headb, out, BATCH, D, NC);
}

// Round 3
// 6480.632 us; speedup vs baseline: 3.7336x; 1.2912x over previous
//
#include <hip/hip_runtime.h>
#include <math.h>

#define D 768
#define NH 12
#define DH 64
#define DEPTH 12
#define TMAX 197
#define NPATCH 196
#define BATCH 32
#define DFF 3072
#define NC 1000
#define QSTRIDE 2304   // 3*D
#define SCALE 0.125f
#define EPSF 1e-6f

typedef __bf16 bf16x8 __attribute__((ext_vector_type(8)));
typedef float f32x4 __attribute__((ext_vector_type(4)));
typedef short sshort8 __attribute__((ext_vector_type(8)));

// ---------------- bf16 split helpers ----------------

__device__ __forceinline__ short f2bf(float x) {
  unsigned u = __float_as_uint(x);
  u = u + 0x7fffu + ((u >> 16) & 1u);
  return (short)(u >> 16);
}
__device__ __forceinline__ float bf2f(short h) {
  return __uint_as_float(((unsigned)(unsigned short)h) << 16);
}
__device__ __forceinline__ void bsplit(float x, short* hp, short* lp) {
  short h = f2bf(x);
  *hp = h;
  *lp = f2bf(x - bf2f(h));
}

// global -> LDS direct copy, 16B per lane. LDS dest must be wave-uniform base.
__device__ __forceinline__ void gll16(const void* g, void* l) {
  __builtin_amdgcn_global_load_lds(
      (const __attribute__((address_space(1))) void*)g,
      (__attribute__((address_space(3))) void*)l, 16, 0, 0);
}

// ---------------- utility ----------------

__device__ __forceinline__ float block_reduce_sum(float v, float* red, int tid) {
  red[tid] = v; __syncthreads();
  #pragma unroll
  for (int o = 128; o > 0; o >>= 1) { if (tid < o) red[tid] += red[tid + o]; __syncthreads(); }
  float r = red[0]; __syncthreads();
  return r;
}

__global__ void fail_kernel(float* out) { out[0] = 1.0e6f; }

__global__ void init_kernel(int* si, float* sf) {
  si[0] = TMAX;  // tok (N+1)
  si[1] = 0;     // prev_mass valid
  si[2] = 0;     // prune flag this layer
  sf[0] = 0.f;   // prev_mass
}

// ---------------- weight split/transpose ----------------
// W f32 [K][N] -> Wpk bf16 [N][2][K]  (hi plane, lo plane; k contiguous)
__global__ void wsplit_t(const float* __restrict__ W, short* __restrict__ Wpk,
                         int K, int N) {
  __shared__ float t[32][33];
  int n0 = blockIdx.x * 32, k0 = blockIdx.y * 32;
  int tid = threadIdx.x;
  int kk = tid >> 3, n4 = (tid & 7) * 4;
  float4 v = *(const float4*)(W + (size_t)(k0 + kk) * N + n0 + n4);
  t[kk][n4] = v.x; t[kk][n4 + 1] = v.y; t[kk][n4 + 2] = v.z; t[kk][n4 + 3] = v.w;
  __syncthreads();
  int nn = tid >> 3, k4 = (tid & 7) * 4;
  short* dh = Wpk + (size_t)(n0 + nn) * 2 * K + k0 + k4;
  short* dl = dh + K;
  #pragma unroll
  for (int c = 0; c < 4; ++c) bsplit(t[k4 + c][nn], &dh[c], &dl[c]);
}

// W f32 [N][K] (already k-contiguous) -> Wpk [N][2][K]
__global__ void wsplit_nt(const float* __restrict__ W, short* __restrict__ Wpk, int K) {
  const float* src = W + (size_t)blockIdx.x * K;
  short* dh = Wpk + (size_t)blockIdx.x * 2 * K;
  short* dl = dh + K;
  for (int k = threadIdx.x; k < K; k += 256) bsplit(src[k], &dh[k], &dl[k]);
}

// ---------------- embed ----------------

__global__ void im2col_kernel(const float* __restrict__ x, short* __restrict__ Impk) {
  int p = blockIdx.x, b = blockIdx.y;
  int py = p / 14, px = p % 14;
  short* dst = Impk + ((size_t)b * NPATCH + p) * 1536;
  for (int k = threadIdx.x; k < D; k += 256) {
    int c = k >> 8; int rem = k & 255; int i = rem >> 4; int j = rem & 15;
    float v = x[(((size_t)b * 3 + c) * 224 + py * 16 + i) * 224 + px * 16 + j];
    bsplit(v, &dst[k], &dst[768 + k]);
  }
}

__global__ void assemble_kernel(const float* __restrict__ PE, const float* __restrict__ cls,
                                const float* __restrict__ pos, float* __restrict__ X) {
  int t = blockIdx.x, b = blockIdx.y; int tid = threadIdx.x;
  float* xp = X + ((size_t)(b * TMAX) + t) * D;
  for (int k = tid; k < D; k += 256) {
    float v = (t == 0) ? cls[k] : PE[((size_t)(b * NPATCH) + (t - 1)) * D + k];
    xp[k] = v + pos[(size_t)t * D + k];
  }
}

// ---------------- layernorm ----------------

__global__ void ln_kernel(const float* __restrict__ Xin, short* __restrict__ XNpk,
                          const float* __restrict__ wgt, const float* __restrict__ bsh,
                          const int* __restrict__ si) {
  int row = blockIdx.x;
  if ((row % TMAX) >= si[0]) return;
  __shared__ float red[256];
  int tid = threadIdx.x;
  const float* xp = Xin + (size_t)row * D;
  float v0 = xp[tid], v1 = xp[tid + 256], v2 = xp[tid + 512];
  float mu = block_reduce_sum(v0 + v1 + v2, red, tid) * (1.0f / 768.0f);
  float d0 = v0 - mu, d1 = v1 - mu, d2 = v2 - mu;
  float var = block_reduce_sum(d0 * d0 + d1 * d1 + d2 * d2, red, tid) * (1.0f / 768.0f);
  float inv = 1.0f / sqrtf(var + EPSF);
  short* op = XNpk + (size_t)row * 1536;
  float y0 = d0 * inv * wgt[tid] + bsh[tid];
  float y1 = d1 * inv * wgt[tid + 256] + bsh[tid + 256];
  float y2 = d2 * inv * wgt[tid + 512] + bsh[tid + 512];
  bsplit(y0, &op[tid], &op[768 + tid]);
  bsplit(y1, &op[tid + 256], &op[768 + tid + 256]);
  bsplit(y2, &op[tid + 512], &op[768 + tid + 512]);
}

__global__ void lnfinal_kernel(const float* __restrict__ X, float* __restrict__ CLSb,
                               const float* __restrict__ wgt, const float* __restrict__ bsh) {
  int b = blockIdx.x; int tid = threadIdx.x;
  __shared__ float red[256];
  const float* xp = X + (size_t)b * TMAX * D;  // row t=0
  float v0 = xp[tid], v1 = xp[tid + 256], v2 = xp[tid + 512];
  float mu = block_reduce_sum(v0 + v1 + v2, red, tid) * (1.0f / 768.0f);
  float d0 = v0 - mu, d1 = v1 - mu, d2 = v2 - mu;
  float var = block_reduce_sum(d0 * d0 + d1 * d1 + d2 * d2, red, tid) * (1.0f / 768.0f);
  float inv = 1.0f / sqrtf(var + EPSF);
  float* op = CLSb + (size_t)b * D;
  op[tid]       = d0 * inv * wgt[tid]       + bsh[tid];
  op[tid + 256] = d1 * inv * wgt[tid + 256] + bsh[tid + 256];
  op[tid + 512] = d2 * inv * wgt[tid + 512] + bsh[tid + 512];
}

// ---------------- MFMA GEMM (bf16x3 split emulation of f32) ----------------

#define GTM 128
#define GTN 128
#define GTK 32

template<int EPI>
__global__ __launch_bounds__(256)
void mgemm_kernel(const short* __restrict__ Apk, const short* __restrict__ Bpk,
                  const float* __restrict__ bias, const float* __restrict__ Rsrc,
                  float* __restrict__ Cf, short* __restrict__ Cpk,
                  int M, int K, int N) {
  __shared__ char lds[65536];  // 2 buffers x (A 16KB | B 16KB)
  const int tid = threadIdx.x;
  const int ln = tid & 63;
  const int wv = tid >> 6;
  const int wm = wv >> 1, wn = wv & 1;
  const int m0 = blockIdx.y * GTM, n0 = blockIdx.x * GTN;
  const int lm = ln & 15, kc = ln >> 4;
  const size_t rs = 2 * (size_t)K;

  f32x4 acc[4][4];
  f32x4 zv = {0.f, 0.f, 0.f, 0.f};
  #pragma unroll
  for (int i = 0; i < 4; ++i)
    #pragma unroll
    for (int j = 0; j < 4; ++j) acc[i][j] = zv;

  auto stage = [&](int k0, int buf) {
    char* base = lds + (buf << 15);
    #pragma unroll
    for (int i = 0; i < 4; ++i) {
      int s = (i << 8) + tid;          // physical 16B slot index
      int r = s >> 3;                  // row 0..127
      int sl = (s & 7) ^ (r & 7);      // logical slot (inverse swizzle)
      size_t eoff = (size_t)(sl >> 2) * K + (size_t)(k0 + ((sl & 3) << 3));
      int ldsoff = ((i << 8) + (tid & 192)) << 4;  // wave-uniform
      gll16(Apk + (size_t)(m0 + r) * rs + eoff, base + ldsoff);
      gll16(Bpk + (size_t)(n0 + r) * rs + eoff, base + 16384 + ldsoff);
    }
  };

  const int nk = K / GTK;
  stage(0, 0);
  for (int kt = 0; kt < nk; ++kt) {
    __syncthreads();                    // drains vmcnt -> staged tile visible
    if (kt + 1 < nk) stage((kt + 1) * GTK, (kt + 1) & 1);
    const char* pa = lds + ((kt & 1) << 15);
    const char* pb = pa + 16384;
    bf16x8 bh[4], bl[4];
    #pragma unroll
    for (int j = 0; j < 4; ++j) {
      int c = wn * 64 + j * 16 + lm;
      int bo = c * 128 + ((kc ^ (c & 7)) << 4);
      bh[j] = *(const bf16x8*)(pb + bo);
      bl[j] = *(const bf16x8*)(pb + (bo ^ 64));
    }
    #pragma unroll
    for (int i = 0; i < 4; ++i) {
      int r = wm * 64 + i * 16 + lm;
      int ao = r * 128 + ((kc ^ (r & 7)) << 4);
      bf16x8 ah = *(const bf16x8*)(pa + ao);
      bf16x8 al = *(const bf16x8*)(pa + (ao ^ 64));
      #pragma unroll
      for (int j = 0; j < 4; ++j) {
        acc[i][j] = __builtin_amdgcn_mfma_f32_16x16x32_bf16(ah, bh[j], acc[i][j], 0, 0, 0);
        acc[i][j] = __builtin_amdgcn_mfma_f32_16x16x32_bf16(ah, bl[j], acc[i][j], 0, 0, 0);
        acc[i][j] = __builtin_amdgcn_mfma_f32_16x16x32_bf16(al, bh[j], acc[i][j], 0, 0, 0);
      }
    }
  }

  // epilogue: C/D layout col = ln&15, row = (ln>>4)*4 + t
  #pragma unroll
  for (int i = 0; i < 4; ++i) {
    #pragma unroll
    for (int t = 0; t < 4; ++t) {
      int m = m0 + wm * 64 + i * 16 + kc * 4 + t;
      if (m >= M) continue;
      #pragma unroll
      for (int j = 0; j < 4; ++j) {
        int n = n0 + wn * 64 + j * 16 + lm;
        float v = acc[i][j][t] + bias[n];
        if (EPI == 1) v += Rsrc[(size_t)m * N + n];
        if (EPI == 2) {
          v = v * 0.5f * (1.0f + erff(v * 0.70710678118654752f));
          short h = f2bf(v);
          Cpk[(size_t)m * 2 * N + n] = h;
          Cpk[(size_t)m * 2 * N + N + n] = f2bf(v - bf2f(h));
        } else {
          Cf[(size_t)m * N + n] = v;
        }
      }
    }
  }
}

// ---------------- f32 GEMM (head only) ----------------

#define BM 128
#define BN 64
#define BK 16

__global__ __launch_bounds__(256, 2)
void gemm_kernel(const float* __restrict__ A, const float* __restrict__ Bw,
                 const float* __restrict__ bias, float* __restrict__ C,
                 int M, int K, int N) {
  __shared__ float As[BK][BM + 4];
  __shared__ float Bs[BK][BN];
  int tid = threadIdx.x;
  int tx = tid & 15;
  int ty = tid >> 4;
  int m0 = blockIdx.y * BM;
  int n0 = blockIdx.x * BN;
  float acc[8][4];
  #pragma unroll
  for (int i = 0; i < 8; ++i)
    #pragma unroll
    for (int j = 0; j < 4; ++j) acc[i][j] = 0.f;
  const int lkA = tid & 15;
  const int lmA = tid >> 4;
  const int lnB = tid & 63;
  const int lkB = tid >> 6;
  for (int k0 = 0; k0 < K; k0 += BK) {
    #pragma unroll
    for (int r = 0; r < 8; ++r) {
      int ml = r * 16 + lmA;
      int m = m0 + ml;
      float va = 0.f;
      if (m < M) va = A[(size_t)m * K + k0 + lkA];
      As[lkA][ml] = va;
    }
    #pragma unroll
    for (int r = 0; r < 4; ++r) {
      int kk = r * 4 + lkB;
      int n = n0 + lnB;
      float vb = 0.f;
      if (n < N) vb = Bw[(size_t)(k0 + kk) * N + n];
      Bs[kk][lnB] = vb;
    }
    __syncthreads();
    #pragma unroll
    for (int kk = 0; kk < BK; ++kk) {
      const float4 b4 = *(const float4*)(&Bs[kk][tx * 4]);
      const float4 a0 = *(const float4*)(&As[kk][ty * 8]);
      const float4 a1 = *(const float4*)(&As[kk][ty * 8 + 4]);
      const float a[8] = {a0.x, a0.y, a0.z, a0.w, a1.x, a1.y, a1.z, a1.w};
      const float bb[4] = {b4.x, b4.y, b4.z, b4.w};
      #pragma unroll
      for (int i = 0; i < 8; ++i)
        #pragma unroll
        for (int j = 0; j < 4; ++j)
          acc[i][j] = fmaf(a[i], bb[j], acc[i][j]);
    }
    __syncthreads();
  }
  #pragma unroll
  for (int i = 0; i < 8; ++i) {
    int m = m0 + ty * 8 + i;
    if (m >= M) continue;
    #pragma unroll
    for (int j = 0; j < 4; ++j) {
      int n = n0 + tx * 4 + j;
      if (n >= N) continue;
      C[(size_t)m * N + n] = acc[i][j] + bias[n];
    }
  }
}

// ---------------- MFMA attention (flash, bf16x3 split) ----------------
// block = 256 thr = 4 waves; one (b,h), 64 q-rows (wave w: rows w*16..+15).
// K LDS [k][d] bf16 hi/lo; V LDS transposed [d][k] hi/lo; XOR slot swizzle.
// P routed via per-wave LDS buffer into A-frag layout.

#define QT 64
#define KVT 64

__global__ __launch_bounds__(256)
void mattn_kernel(const float* __restrict__ QKV, short* __restrict__ AOpk,
                  const int* __restrict__ si) {
  const int tok = si[0];
  const int bh = blockIdx.x; const int b = bh / NH, h = bh % NH;
  const int q0 = blockIdx.y * QT;
  if (q0 >= tok) return;
  __shared__ short Kh[4096], Kl[4096], Vth[4096], Vtl[4096];  // 8KB each
  __shared__ short Pb[8192];                                   // 4 waves x (hi 1024 | lo 1024)
  const int tid = threadIdx.x;
  const int l = tid & 63, w = tid >> 6;
  const int lm = l & 15, lg = l >> 4;

  // Q fragments (A-layout: row = lm, k(d) = c*32 + lg*8 + j)
  bf16x8 qh[2], ql[2];
  {
    int qrow = q0 + w * 16 + lm;
    if (qrow >= TMAX) qrow = TMAX - 1;
    const float* qp = QKV + (size_t)(b * TMAX + qrow) * QSTRIDE + h * DH + lg * 8;
    #pragma unroll
    for (int c = 0; c < 2; ++c) {
      sshort8 hs, ls;
      #pragma unroll
      for (int j = 0; j < 8; ++j) {
        float v = qp[c * 32 + j];
        short hh = f2bf(v);
        hs[j] = hh;
        ls[j] = f2bf(v - bf2f(hh));
      }
      qh[c] = __builtin_bit_cast(bf16x8, hs);
      ql[c] = __builtin_bit_cast(bf16x8, ls);
    }
  }

  float mrun[4], lrun[4];
  f32x4 oacc[4];
  f32x4 zv = {0.f, 0.f, 0.f, 0.f};
  #pragma unroll
  for (int t = 0; t < 4; ++t) { mrun[t] = -1e30f; lrun[t] = 0.f; }
  #pragma unroll
  for (int j = 0; j < 4; ++j) oacc[j] = zv;

  // staging mapping: 4x4 block per thread
  const int r0 = (tid >> 4) * 4;     // 0..60
  const int td4 = (tid & 15) * 4;    // 0..60

  for (int j0 = 0; j0 < tok; j0 += KVT) {
    // ---- stage K and V^T (hi/lo) ----
    {
      float vbuf[16];
      #pragma unroll
      for (int i = 0; i < 4; ++i) {
        int gr = j0 + r0 + i; if (gr >= TMAX) gr = TMAX - 1;
        const float* kp = QKV + (size_t)(b * TMAX + gr) * QSTRIDE + D + h * DH + td4;
        float4 kv = *(const float4*)kp;
        short4 sh, sl;
        sh.x = f2bf(kv.x); sl.x = f2bf(kv.x - bf2f(sh.x));
        sh.y = f2bf(kv.y); sl.y = f2bf(kv.y - bf2f(sh.y));
        sh.z = f2bf(kv.z); sl.z = f2bf(kv.z - bf2f(sh.z));
        sh.w = f2bf(kv.w); sl.w = f2bf(kv.w - bf2f(sh.w));
        int r = r0 + i;
        int so = r * 64 + (((td4 >> 3) ^ (r & 7)) << 3) + (td4 & 7);
        *(short4*)(Kh + so) = sh;
        *(short4*)(Kl + so) = sl;
        const float* vp = QKV + (size_t)(b * TMAX + gr) * QSTRIDE + 2 * D + h * DH + td4;
        float4 vv = *(const float4*)vp;
        vbuf[i * 4 + 0] = vv.x; vbuf[i * 4 + 1] = vv.y;
        vbuf[i * 4 + 2] = vv.z; vbuf[i * 4 + 3] = vv.w;
      }
      #pragma unroll
      for (int dd = 0; dd < 4; ++dd) {
        int d = td4 + dd;
        short4 sh, sl;
        float c0 = vbuf[dd], c1 = vbuf[4 + dd], c2 = vbuf[8 + dd], c3 = vbuf[12 + dd];
        sh.x = f2bf(c0); sl.x = f2bf(c0 - bf2f(sh.x));
        sh.y = f2bf(c1); sl.y = f2bf(c1 - bf2f(sh.y));
        sh.z = f2bf(c2); sl.z = f2bf(c2 - bf2f(sh.z));
        sh.w = f2bf(c3); sl.w = f2bf(c3 - bf2f(sh.w));
        int so = d * 64 + (((r0 >> 3) ^ (d & 7)) << 3) + (r0 & 7);
        *(short4*)(Vth + so) = sh;
        *(short4*)(Vtl + so) = sl;
      }
    }
    __syncthreads();

    // ---- S = Q K^T (3-product split) ----
    f32x4 sacc[4];
    #pragma unroll
    for (int jk = 0; jk < 4; ++jk) sacc[jk] = zv;
    #pragma unroll
    for (int c = 0; c < 2; ++c) {
      #pragma unroll
      for (int jk = 0; jk < 4; ++jk) {
        int row = jk * 16 + lm;
        int so = row * 64 + (((c * 4 + lg) ^ (row & 7)) << 3);
        bf16x8 kbh = *(const bf16x8*)(Kh + so);
        bf16x8 kbl = *(const bf16x8*)(Kl + so);
        sacc[jk] = __builtin_amdgcn_mfma_f32_16x16x32_bf16(qh[c], kbh, sacc[jk], 0, 0, 0);
        sacc[jk] = __builtin_amdgcn_mfma_f32_16x16x32_bf16(qh[c], kbl, sacc[jk], 0, 0, 0);
        sacc[jk] = __builtin_amdgcn_mfma_f32_16x16x32_bf16(ql[c], kbh, sacc[jk], 0, 0, 0);
      }
    }

    // ---- online softmax (per q-row; row q held by 16 lanes of group lg) ----
    float p[4][4];
    #pragma unroll
    for (int jk = 0; jk < 4; ++jk) {
      bool valid = (j0 + jk * 16 + lm) < tok;
      #pragma unroll
      for (int t = 0; t < 4; ++t)
        p[jk][t] = valid ? sacc[jk][t] * SCALE : -1e30f;
    }
    float mt[4], mnew[4], co[4], rs[4];
    #pragma unroll
    for (int t = 0; t < 4; ++t) {
      mt[t] = fmaxf(fmaxf(p[0][t], p[1][t]), fmaxf(p[2][t], p[3][t]));
      #pragma unroll
      for (int off = 1; off < 16; off <<= 1)
        mt[t] = fmaxf(mt[t], __shfl_xor(mt[t], off, 16));
      mnew[t] = fmaxf(mrun[t], mt[t]);
      co[t] = expf(mrun[t] - mnew[t]);
      rs[t] = 0.f;
    }
    #pragma unroll
    for (int jk = 0; jk < 4; ++jk)
      #pragma unroll
      for (int t = 0; t < 4; ++t) {
        p[jk][t] = expf(p[jk][t] - mnew[t]);
        rs[t] += p[jk][t];
      }
    #pragma unroll
    for (int t = 0; t < 4; ++t) {
      #pragma unroll
      for (int off = 1; off < 16; off <<= 1)
        rs[t] += __shfl_xor(rs[t], off, 16);
      lrun[t] = lrun[t] * co[t] + rs[t];
      mrun[t] = mnew[t];
    }
    #pragma unroll
    for (int jd = 0; jd < 4; ++jd)
      #pragma unroll
      for (int t = 0; t < 4; ++t) oacc[jd][t] *= co[t];

    // ---- P -> per-wave LDS (bf16 hi/lo, A-frag layout) ----
    short* Pw = Pb + w * 2048;
    #pragma unroll
    for (int jk = 0; jk < 4; ++jk)
      #pragma unroll
      for (int t = 0; t < 4; ++t) {
        int q = lg * 4 + t;
        int col = jk * 16 + lm;
        short hh = f2bf(p[jk][t]);
        short hl = f2bf(p[jk][t] - bf2f(hh));
        int so = q * 64 + (((col >> 3) ^ (q & 7)) << 3) + (col & 7);
        Pw[so] = hh;
        Pw[1024 + so] = hl;
      }

    // ---- PV (3-product split) ----
    #pragma unroll
    for (int c = 0; c < 2; ++c) {
      int aro = lm * 64 + (((c * 4 + lg) ^ (lm & 7)) << 3);
      bf16x8 pah = *(const bf16x8*)(Pw + aro);
      bf16x8 pal = *(const bf16x8*)(Pw + 1024 + aro);
      #pragma unroll
      for (int jd = 0; jd < 4; ++jd) {
        int d = jd * 16 + lm;
        int so = d * 64 + (((c * 4 + lg) ^ (d & 7)) << 3);
        bf16x8 vbh = *(const bf16x8*)(Vth + so);
        bf16x8 vbl = *(const bf16x8*)(Vtl + so);
        oacc[jd] = __builtin_amdgcn_mfma_f32_16x16x32_bf16(pah, vbh, oacc[jd], 0, 0, 0);
        oacc[jd] = __builtin_amdgcn_mfma_f32_16x16x32_bf16(pah, vbl, oacc[jd], 0, 0, 0);
        oacc[jd] = __builtin_amdgcn_mfma_f32_16x16x32_bf16(pal, vbh, oacc[jd], 0, 0, 0);
      }
    }
    __syncthreads();
  }

  // ---- store O (split bf16), rows masked to tok ----
  #pragma unroll
  for (int t = 0; t < 4; ++t) {
    int q = q0 + w * 16 + lg * 4 + t;
    if (q >= tok) continue;
    float inv = 1.0f / lrun[t];
    short* op = AOpk + (size_t)(b * TMAX + q) * 1536 + h * DH;
    #pragma unroll
    for (int jd = 0; jd < 4; ++jd) {
      int d = jd * 16 + lm;
      float y = oacc[jd][t] * inv;
      short hh = f2bf(y);
      op[d] = hh;
      op[768 + d] = f2bf(y - bf2f(hh));
    }
  }
}

// cls attention row per (b,h)
__global__ void clsrow_kernel(const float* __restrict__ QKV, float* __restrict__ Pcls,
                              const int* __restrict__ si) {
  int tok = si[0];
  int bh = blockIdx.x; int b = bh / NH, h = bh % NH;
  int tid = threadIdx.x;
  __shared__ float q[DH];
  __shared__ float red[256];
  if (tid < DH) q[tid] = QKV[((size_t)(b * TMAX)) * QSTRIDE + h * DH + tid];
  __syncthreads();
  float sval = -1e30f;
  if (tid < tok) {
    const float* kp = QKV + ((size_t)(b * TMAX) + tid) * QSTRIDE + D + h * DH;
    float a = 0.f;
    #pragma unroll
    for (int dd = 0; dd < DH; ++dd) a = fmaf(q[dd], kp[dd], a);
    sval = a * SCALE;
  }
  red[tid] = sval; __syncthreads();
  #pragma unroll
  for (int o = 128; o > 0; o >>= 1) { if (tid < o) red[tid] = fmaxf(red[tid], red[tid + o]); __syncthreads(); }
  float mx = red[0]; __syncthreads();
  float e = (tid < tok) ? expf(sval - mx) : 0.f;
  red[tid] = e; __syncthreads();
  #pragma unroll
  for (int o = 128; o > 0; o >>= 1) { if (tid < o) red[tid] += red[tid + o]; __syncthreads(); }
  if (tid < tok) Pcls[(size_t)bh * TMAX + tid] = e / red[0];
}

__global__ void aclsmean_kernel(const float* __restrict__ Pcls, float* __restrict__ Acls,
                                const int* __restrict__ si) {
  int tok = si[0]; int b = blockIdx.x; int tid = threadIdx.x;
  if (tid < tok) {
    float s = 0.f;
    #pragma unroll
    for (int h = 0; h < NH; ++h) s += Pcls[((size_t)b * NH + h) * TMAX + tid];
    Acls[b * TMAX + tid] = s * (1.0f / 12.0f);
  }
}

__global__ void vmean_kernel(const float* __restrict__ QKV, float* __restrict__ Vm,
                             const int* __restrict__ si) {
  int tok = si[0];
  int t = blockIdx.x, b = blockIdx.y;
  if (t >= tok) return;
  int d = threadIdx.x;  // 64
  const float* vp = QKV + ((size_t)(b * TMAX + t)) * QSTRIDE + 2 * D;
  float s = 0.f;
  #pragma unroll
  for (int h = 0; h < NH; ++h) s += vp[h * DH + d];
  Vm[((size_t)b * TMAX + t) * DH + d] = s * (1.0f / 12.0f);
}

// ---------------- pruning stats ----------------

__global__ void stats_kernel(const float* __restrict__ Vm, const float* __restrict__ Acls,
                             float* __restrict__ Jbuf, float* __restrict__ Jsum,
                             float* __restrict__ rhot, const int* __restrict__ si) {
  int tok = si[0]; int N = tok - 1;
  if (N <= 16) return;
  int b = blockIdx.x; int tid = threadIdx.x;
  __shared__ float red[256];
  __shared__ float vmean[DH];
  __shared__ float Vn[NPATCH];
  const float* vb = Vm + (size_t)b * TMAX * DH;

  float x0 = 0.f;
  if (tid < DH) { float v = vb[tid]; x0 = v * v; }
  red[tid] = x0; __syncthreads();
  #pragma unroll
  for (int o = 128; o > 0; o >>= 1) { if (tid < o) red[tid] += red[tid + o]; __syncthreads(); }
  if (tid == 0) rhot[b] = 1.0f + Acls[b * TMAX] * sqrtf(red[0]);
  __syncthreads();

  int d = tid & 63, part = tid >> 6;
  float s = 0.f;
  for (int t = 1 + part; t <= N; t += 4) s += vb[(size_t)t * DH + d];
  red[tid] = s; __syncthreads();
  if (tid < DH) vmean[tid] = (red[tid] + red[tid + 64] + red[tid + 128] + red[tid + 192]) / (float)N;
  __syncthreads();

  if (tid < N) {
    const float* vp = vb + (size_t)(tid + 1) * DH;
    float a = 0.f;
    #pragma unroll
    for (int dd = 0; dd < DH; ++dd) { float z = vp[dd] - vmean[dd]; a = fmaf(z, z, a); }
    Vn[tid] = sqrtf(a);
  }
  __syncthreads();

  red[tid] = (tid < N) ? Vn[tid] : 0.f; __syncthreads();
  #pragma unroll
  for (int o = 128; o > 0; o >>= 1) { if (tid < o) red[tid] += red[tid + o]; __syncthreads(); }
  float mu = red[0] / (float)N;
  __syncthreads();
  float dv = (tid < N) ? (Vn[tid] - mu) : 0.f;
  red[tid] = dv * dv; __syncthreads();
  #pragma unroll
  for (int o = 128; o > 0; o >>= 1) { if (tid < o) red[tid] += red[tid + o]; __syncthreads(); }
  float sd = sqrtf(red[0] / (float)(N - 1));
  __syncthreads();

  float Jv = 0.f;
  if (tid < N) {
    float z = (Vn[tid] - mu) / (sd + EPSF);
    z = fmaxf(z, 0.f);
    Jv = Acls[b * TMAX + 1 + tid] * z;
    Jbuf[b * NPATCH + tid] = Jv;
  }
  red[tid] = Jv; __syncthreads();
  #pragma unroll
  for (int o = 128; o > 0; o >>= 1) { if (tid < o) red[tid] += red[tid + o]; __syncthreads(); }
  if (tid == 0) Jsum[b] = red[0];
}

__global__ void decide_kernel(const float* __restrict__ Jbuf, const float* __restrict__ Jsum,
                              const float* __restrict__ rhot, int* __restrict__ keep,
                              int* __restrict__ si, float* __restrict__ sf) {
  int tok = si[0]; int N = tok - 1;
  int tid = threadIdx.x;
  if (N <= 16) { if (tid == 0) si[2] = 0; return; }
  __shared__ float red[256];
  __shared__ float Jms[NPATCH];
  __shared__ int sel[NPATCH];

  red[tid] = (tid < BATCH) ? rhot[tid] : 0.f; __syncthreads();
  #pragma unroll
  for (int o = 128; o > 0; o >>= 1) { if (tid < o) red[tid] += red[tid + o]; __syncthreads(); }
  float rho = red[0] / (float)BATCH; __syncthreads();
  red[tid] = (tid < BATCH) ? Jsum[tid] : 0.f; __syncthreads();
  #pragma unroll
  for (int o = 128; o > 0; o >>= 1) { if (tid < o) red[tid] += red[tid + o]; __syncthreads(); }
  float mass = red[0] / (float)BATCH;
  int prev_valid = si[1];
  float prev = sf[0];
  __syncthreads();

  int N_next = N;
  if (prev_valid) {
    float eta = mass / (prev + EPSF);
    float re = rho * eta;
    re = fminf(fmaxf(re, 0.25f), 4.0f);
    double kr = pow((double)re, -0.01);
    int nn = (int)((double)N * kr);
    N_next = nn > 16 ? nn : 16;
  }
  if (tid == 0) { si[1] = 1; sf[0] = mass; }

  if (N_next < N) {
    if (tid < N) {
      float sJ = 0.f;
      for (int bb = 0; bb < BATCH; ++bb) sJ += Jbuf[bb * NPATCH + tid];
      Jms[tid] = sJ / (float)BATCH;
    }
    __syncthreads();
    if (tid < N) {
      float me = Jms[tid]; int rank = 0;
      for (int s2 = 0; s2 < N; ++s2) {
        float ov = Jms[s2];
        if (ov > me || (ov == me && s2 < tid)) ++rank;
      }
      sel[tid] = (rank < N_next) ? 1 : 0;
    }
    __syncthreads();
    if (tid == 0) {
      int c = 0; keep[c++] = 0;
      for (int t2 = 0; t2 < N; ++t2) if (sel[t2]) keep[c++] = t2 + 1;
      si[0] = N_next + 1;
      si[2] = 1;
    }
  } else {
    if (tid == 0) si[2] = 0;
  }
}

__global__ void gather_kernel(const float* __restrict__ X, float* __restrict__ T,
                              const int* __restrict__ keep, const int* __restrict__ si) {
  if (!si[2]) return;
  int tok = si[0];
  int i = blockIdx.x, b = blockIdx.y;
  if (i >= tok) return;
  int src = keep[i];
  const float* xp = X + ((size_t)(b * TMAX) + src) * D;
  float* tp = T + ((size_t)(b * TMAX) + i) * D;
  int tid = threadIdx.x;
  tp[tid] = xp[tid]; tp[tid + 256] = xp[tid + 256]; tp[tid + 512] = xp[tid + 512];
}

__global__ void copyback_kernel(const float* __restrict__ T, float* __restrict__ X,
                                const int* __restrict__ si) {
  if (!si[2]) return;
  int tok = si[0];
  int i = blockIdx.x, b = blockIdx.y;
  if (i >= tok) return;
  const float* tp = T + ((size_t)(b * TMAX) + i) * D;
  float* xp = X + ((size_t)(b * TMAX) + i) * D;
  int tid = threadIdx.x;
  xp[tid] = tp[tid]; xp[tid + 256] = tp[tid + 256]; xp[tid + 512] = tp[tid + 512];
}

// ---------------- host ----------------

extern "C" void kernel_launch(void* const* d_in, const int* in_sizes, int n_in,
                              void* d_out, int out_size, void* d_ws, size_t ws_size,
                              hipStream_t stream) {
  (void)in_sizes; (void)n_in; (void)out_size;
  const float* x       = (const float*)d_in[0];
  const float* patch_w = (const float*)d_in[1];
  const float* patch_b = (const float*)d_in[2];
  const float* cls_tok = (const float*)d_in[3];
  const float* pos     = (const float*)d_in[4];
  const float* ln1w    = (const float*)d_in[5];
  const float* ln1b    = (const float*)d_in[6];
  const float* qkvw    = (const float*)d_in[7];
  const float* qkvb    = (const float*)d_in[8];
  const float* projw   = (const float*)d_in[9];
  const float* projb   = (const float*)d_in[10];
  const float* ln2w    = (const float*)d_in[11];
  const float* ln2b    = (const float*)d_in[12];
  const float* fc1w    = (const float*)d_in[13];
  const float* fc1b    = (const float*)d_in[14];
  const float* fc2w    = (const float*)d_in[15];
  const float* fc2b    = (const float*)d_in[16];
  const float* normw   = (const float*)d_in[17];
  const float* normb   = (const float*)d_in[18];
  const float* headw   = (const float*)d_in[19];
  const float* headb   = (const float*)d_in[20];
  float* out = (float*)d_out;

  char* w = (char*)d_ws;
  size_t off = 0;
  auto alloc = [&](size_t bytes) -> void* {
    void* p = w + off;
    off += (bytes + 255) & ~(size_t)255;
    return p;
  };
  const size_t MROWS = (size_t)BATCH * TMAX;  // 6304
  float* X    = (float*)alloc(MROWS * D * 4);
  short* XNpk = (short*)alloc(MROWS * 1536 * 2);
  float* QKV  = (float*)alloc(MROWS * QSTRIDE * 4);   // also embed f32 out
  short* AOpk = (short*)alloc(MROWS * 1536 * 2);
  short* Hpk  = (short*)alloc(MROWS * 2 * DFF * 2);   // also Impk / gather TMP
  float* Vm   = (float*)alloc(MROWS * DH * 4);
  float* Pcls = (float*)alloc((size_t)BATCH * NH * TMAX * 4);
  float* Acls = (float*)alloc((size_t)BATCH * TMAX * 4);
  float* Jbuf = (float*)alloc((size_t)BATCH * NPATCH * 4);
  float* Jsum = (float*)alloc(BATCH * 4);
  float* rhot = (float*)alloc(BATCH * 4);
  int*   keep = (int*)alloc(256 * 4);
  int*   si   = (int*)alloc(64 * 4);
  float* sf   = (float*)alloc(64 * 4);
  float* CLS  = (float*)alloc((size_t)BATCH * D * 4);
  short* Wq   = (short*)alloc((size_t)QSTRIDE * 2 * D * 2);
  short* Wp   = (short*)alloc((size_t)D * 2 * D * 2);
  short* W1   = (short*)alloc((size_t)DFF * 2 * D * 2);
  short* W2   = (short*)alloc((size_t)D * 2 * DFF * 2);
  short* Wpat = (short*)alloc((size_t)D * 2 * D * 2);
  short* Impk = Hpk;
  float* TMP  = (float*)Hpk;
  float* Ef32 = QKV;

  if (off > ws_size) {
    fail_kernel<<<1, 1, 0, stream>>>(out);
    return;
  }

  init_kernel<<<1, 1, 0, stream>>>(si, sf);

  // patch embed
  im2col_kernel<<<dim3(NPATCH, BATCH), 256, 0, stream>>>(x, Impk);
  wsplit_nt<<<D, 256, 0, stream>>>(patch_w, Wpat, D);
  mgemm_kernel<0><<<dim3(D / GTN, (BATCH * NPATCH + GTM - 1) / GTM), 256, 0, stream>>>(
      Impk, Wpat, patch_b, nullptr, Ef32, nullptr, BATCH * NPATCH, D, D);
  assemble_kernel<<<dim3(TMAX, BATCH), 256, 0, stream>>>(Ef32, cls_tok, pos, X);

  const int MG = (int)((MROWS + GTM - 1) / GTM);  // 50

  for (int l = 0; l < DEPTH; ++l) {
    const float* l1w = ln1w + l * D;
    const float* l1b = ln1b + l * D;
    const float* qw  = qkvw + (size_t)l * D * 3 * D;
    const float* qb  = qkvb + (size_t)l * 3 * D;
    const float* pw  = projw + (size_t)l * D * D;
    const float* pb  = projb + (size_t)l * D;
    const float* l2w = ln2w + l * D;
    const float* l2b = ln2b + l * D;
    const float* f1w = fc1w + (size_t)l * D * DFF;
    const float* f1b = fc1b + (size_t)l * DFF;
    const float* f2w = fc2w + (size_t)l * DFF * D;
    const float* f2b = fc2b + (size_t)l * D;

    wsplit_t<<<dim3(QSTRIDE / 32, D / 32), 256, 0, stream>>>(qw, Wq, D, QSTRIDE);
    wsplit_t<<<dim3(D / 32, D / 32), 256, 0, stream>>>(pw, Wp, D, D);
    wsplit_t<<<dim3(DFF / 32, D / 32), 256, 0, stream>>>(f1w, W1, D, DFF);
    wsplit_t<<<dim3(D / 32, DFF / 32), 256, 0, stream>>>(f2w, W2, DFF, D);

    ln_kernel<<<BATCH * TMAX, 256, 0, stream>>>(X, XNpk, l1w, l1b, si);
    mgemm_kernel<0><<<dim3(QSTRIDE / GTN, MG), 256, 0, stream>>>(
        XNpk, Wq, qb, nullptr, QKV, nullptr, (int)MROWS, D, QSTRIDE);
    mattn_kernel<<<dim3(BATCH * NH, (TMAX + QT - 1) / QT), 256, 0, stream>>>(QKV, AOpk, si);
    clsrow_kernel<<<BATCH * NH, 256, 0, stream>>>(QKV, Pcls, si);
    aclsmean_kernel<<<BATCH, 256, 0, stream>>>(Pcls, Acls, si);
    vmean_kernel<<<dim3(TMAX, BATCH), 64, 0, stream>>>(QKV, Vm, si);
    mgemm_kernel<1><<<dim3(D / GTN, MG), 256, 0, stream>>>(
        AOpk, Wp, pb, X, X, nullptr, (int)MROWS, D, D);
    ln_kernel<<<BATCH * TMAX, 256, 0, stream>>>(X, XNpk, l2w, l2b, si);
    mgemm_kernel<2><<<dim3(DFF / GTN, MG), 256, 0, stream>>>(
        XNpk, W1, f1b, nullptr, nullptr, Hpk, (int)MROWS, D, DFF);
    mgemm_kernel<1><<<dim3(D / GTN, MG), 256, 0, stream>>>(
        Hpk, W2, f2b, X, X, nullptr, (int)MROWS, DFF, D);
    stats_kernel<<<BATCH, 256, 0, stream>>>(Vm, Acls, Jbuf, Jsum, rhot, si);
    decide_kernel<<<1, 256, 0, stream>>>(Jbuf, Jsum, rhot, keep, si, sf);
    gather_kernel<<<dim3(TMAX, BATCH), 256, 0, stream>>>(X, TMP, keep, si);
    copyback_kernel<<<dim3(TMAX, BATCH), 256, 0, stream>>>(TMP, X, si);
  }

  lnfinal_kernel<<<BATCH, 256, 0, stream>>>(X, CLS, normw, normb);
  gemm_kernel<<<dim3(16, 1), 256, 0, stream>>>(CLS, headw, headb, out, BATCH, D, NC);
}